// Round 4
// baseline (910.770 us; speedup 1.0000x reference)
//
#include <hip/hip_runtime.h>
#include <hip/hip_bf16.h>
#include <math.h>

// N = 100000, E = 3.2M, F_in = 128, H = C = 16. int inputs arrive as int32.
//
// out[d] = dinv[d]*(sum_{s->d} u[s] + u[d]) + b,  u = dinv .* (h @ W).
// R3 result: atomics hit a ~19.4 G line-RMW/s coherence-point ceiling.
// R4: bin edges by dst range (128 nodes/bucket), aggregate in LDS, dense store.

#define F_IN 128
#define H 16
#define NPB 128            // nodes per bucket
#define MAX_NB 800         // max buckets (N <= 102400)

// ---- pass A: bucket histogram (LDS-privatized, few global atomics) ----
__global__ void hist_kernel(const int* __restrict__ dst, int* __restrict__ bcount, int E) {
    __shared__ int h[MAX_NB];
    for (int i = threadIdx.x; i < MAX_NB; i += blockDim.x) h[i] = 0;
    __syncthreads();
    int stride = gridDim.x * blockDim.x;
    for (int e = blockIdx.x * blockDim.x + threadIdx.x; e < E; e += stride)
        atomicAdd(&h[dst[e] >> 7], 1);
    __syncthreads();
    for (int i = threadIdx.x; i < MAX_NB; i += blockDim.x)
        if (h[i]) atomicAdd(&bcount[i], h[i]);
}

// ---- pass B: exclusive scan over NB buckets (single block) ----
__global__ void scan_kernel(const int* __restrict__ bcount, int* __restrict__ base,
                            int* __restrict__ cursor, int NB) {
    __shared__ int s[1024];
    int t = threadIdx.x;
    s[t] = (t < NB) ? bcount[t] : 0;
    __syncthreads();
    for (int off = 1; off < 1024; off <<= 1) {
        int v = (t >= off) ? s[t - off] : 0;
        __syncthreads();
        s[t] += v;
        __syncthreads();
    }
    if (t < NB) {
        int ex = (t == 0) ? 0 : s[t - 1];
        base[t] = ex;
        cursor[t] = ex;
        if (t == NB - 1) base[NB] = s[t];
    }
}

// ---- pass C: bin edges; packed = (dst&127)<<17 | src ----
__global__ void bin_kernel(const int* __restrict__ src, const int* __restrict__ dst,
                           int* __restrict__ cursor, unsigned* __restrict__ packed, int E) {
    __shared__ int h[MAX_NB];
    long long e0 = (long long)E * blockIdx.x / gridDim.x;
    long long e1 = (long long)E * (blockIdx.x + 1) / gridDim.x;
    for (int i = threadIdx.x; i < MAX_NB; i += blockDim.x) h[i] = 0;
    __syncthreads();
    for (long long e = e0 + threadIdx.x; e < e1; e += blockDim.x)
        atomicAdd(&h[dst[e] >> 7], 1);
    __syncthreads();
    for (int i = threadIdx.x; i < MAX_NB; i += blockDim.x) {
        int c = h[i];
        if (c) h[i] = atomicAdd(&cursor[i], c);   // h[i] becomes this block's local cursor
    }
    __syncthreads();
    for (long long e = e0 + threadIdx.x; e < e1; e += blockDim.x) {
        int d = dst[e];
        int b = d >> 7;
        int pos = atomicAdd(&h[b], 1);
        packed[pos] = (unsigned)src[e] | ((unsigned)(d & 127) << 17);
    }
}

// ---- degree + dinv from the binned list (LDS counts, no global atomics) ----
__global__ void degdinv_kernel(const unsigned* __restrict__ packed, const int* __restrict__ base,
                               float* __restrict__ dinv, int N) {
    __shared__ int cnt[NPB];
    int b = blockIdx.x;
    if (threadIdx.x < NPB) cnt[threadIdx.x] = 0;
    __syncthreads();
    int e0 = base[b], e1 = base[b + 1];
    for (int i = e0 + threadIdx.x; i < e1; i += blockDim.x)
        atomicAdd(&cnt[packed[i] >> 17], 1);
    __syncthreads();
    if (threadIdx.x < NPB) {
        int node = b * NPB + threadIdx.x;
        if (node < N) dinv[node] = rsqrtf(1.0f + (float)cnt[threadIdx.x]);
    }
}

// ---- u[i][j] = dinv[i] * sum_k x[i][k]*W1[k][j]; x tile via LDS float4 ----
#define XPAD 132
__global__ void xw1_kernel(const float* __restrict__ x, const float* __restrict__ W1,
                           const float* __restrict__ dinv, float* __restrict__ u, int n) {
    __shared__ float sW1[F_IN * H];
    __shared__ float sx[16 * XPAD];
    for (int t = threadIdx.x; t < F_IN * H; t += blockDim.x) sW1[t] = W1[t];

    int basei = blockIdx.x * 16;
    for (int idx = threadIdx.x; idx < 512; idx += 256) {
        int r = idx >> 5;
        int kk = (idx & 31) << 2;
        int row = basei + r;
        float4 v = make_float4(0.f, 0.f, 0.f, 0.f);
        if (row < n) v = *(const float4*)(x + (size_t)row * F_IN + kk);
        *(float4*)(sx + r * XPAD + kk) = v;
    }
    __syncthreads();

    int r = threadIdx.x >> 4;
    int j = threadIdx.x & 15;
    int row = basei + r;
    if (row >= n) return;

    const float* xr = sx + r * XPAD;
    float acc = 0.0f;
#pragma unroll 16
    for (int k = 0; k < F_IN; k++) acc += xr[k] * sW1[k * H + j];
    u[(size_t)row * H + j] = dinv[row] * acc;
}

// ---- binned scatter: gather u[src], LDS-accumulate, dense store (no global atomics) ----
__global__ void scatter_bin_kernel(const unsigned* __restrict__ packed, const int* __restrict__ base,
                                   const float* __restrict__ u, float* __restrict__ agg, int N) {
    __shared__ float acc[NPB * H];   // 8 KB
    int b = blockIdx.x;
    for (int i = threadIdx.x; i < NPB * H; i += 256) acc[i] = 0.0f;
    __syncthreads();

    int e0 = base[b], e1 = base[b + 1];
    int j = threadIdx.x & 15;
    int g = threadIdx.x >> 4;        // 16 edge-groups per block
    for (int i = e0 + g; i < e1; i += 16) {
        unsigned p = packed[i];
        int s = p & 0x1FFFF;
        int dl = p >> 17;
        atomicAdd(&acc[dl * H + j], u[(size_t)s * H + j]);
    }
    __syncthreads();

    for (int i = threadIdx.x; i < NPB * H; i += 256) {
        int node = b * NPB + (i >> 4);
        if (node < N) agg[(size_t)node * H + (i & 15)] = acc[i];
    }
}

// ---- h1 = relu(dinv*(agg+u)+b1); u2 = dinv*(h1@W2) overwrites u ----
__global__ void finalize1_kernel(const float* __restrict__ agg, float* __restrict__ u,
                                 const float* __restrict__ dinv, const float* __restrict__ b1,
                                 const float* __restrict__ W2, int n) {
    __shared__ float sW2[H * H];
    __shared__ float sb1[H];
    if (threadIdx.x < H * H) sW2[threadIdx.x] = W2[threadIdx.x];
    if (threadIdx.x < H) sb1[threadIdx.x] = b1[threadIdx.x];
    __syncthreads();

    int row = blockIdx.x * 16 + (threadIdx.x >> 4);
    int j = threadIdx.x & 15;
    if (row >= n) return;

    float di = dinv[row];
    float h = di * (agg[(size_t)row * H + j] + u[(size_t)row * H + j]) + sb1[j];
    h = fmaxf(h, 0.0f);

    float acc = 0.0f;
#pragma unroll
    for (int k = 0; k < H; k++) {
        float hk = __shfl(h, k, 16);
        acc += hk * sW2[k * H + j];
    }
    u[(size_t)row * H + j] = di * acc;
}

// ---- v = dinv*(agg+u)+b2; out = log_softmax(v) ----
__global__ void finalize2_kernel(const float* __restrict__ agg, const float* __restrict__ u,
                                 const float* __restrict__ dinv, const float* __restrict__ b2,
                                 float* __restrict__ out, int n) {
    __shared__ float sb2[H];
    if (threadIdx.x < H) sb2[threadIdx.x] = b2[threadIdx.x];
    __syncthreads();

    int row = blockIdx.x * 16 + (threadIdx.x >> 4);
    int j = threadIdx.x & 15;
    if (row >= n) return;

    float di = dinv[row];
    float v = di * (agg[(size_t)row * H + j] + u[(size_t)row * H + j]) + sb2[j];

    float m = v;
#pragma unroll
    for (int off = 8; off >= 1; off >>= 1) m = fmaxf(m, __shfl_xor(m, off, 16));
    float ex = __expf(v - m);
    float s = ex;
#pragma unroll
    for (int off = 8; off >= 1; off >>= 1) s += __shfl_xor(s, off, 16);

    out[(size_t)row * H + j] = v - m - __logf(s);
}

extern "C" void kernel_launch(void* const* d_in, const int* in_sizes, int n_in,
                              void* d_out, int out_size, void* d_ws, size_t ws_size,
                              hipStream_t stream) {
    const float* x = (const float*)d_in[0];
    const int* edge_index = (const int*)d_in[1];
    const float* W1 = (const float*)d_in[2];
    const float* b1 = (const float*)d_in[3];
    const float* W2 = (const float*)d_in[4];
    const float* b2 = (const float*)d_in[5];
    float* out = (float*)d_out;

    const int N = in_sizes[0] / F_IN;        // 100000
    const int E = in_sizes[1] / 2;           // 3200000
    const int* src = edge_index;
    const int* dst = edge_index + E;
    const int NB = (N + NPB - 1) / NPB;      // 782

    // ws layout (4B units): dinv[N] | u[16N] | agg[16N] | packed[E] | bcount[NB] | base[NB+1] | cursor[NB]
    float* dinv = (float*)d_ws;
    float* u = dinv + N;
    float* agg = u + (size_t)N * H;
    unsigned* packed = (unsigned*)(agg + (size_t)N * H);
    int* bcount = (int*)(packed + E);
    int* base = bcount + NB;
    int* cursor = base + NB + 1;

    hipMemsetAsync(bcount, 0, NB * sizeof(int), stream);

    hist_kernel<<<320, 256, 0, stream>>>(dst, bcount, E);
    scan_kernel<<<1, 1024, 0, stream>>>(bcount, base, cursor, NB);
    bin_kernel<<<320, 256, 0, stream>>>(src, dst, cursor, packed, E);
    degdinv_kernel<<<NB, 256, 0, stream>>>(packed, base, dinv, N);

    xw1_kernel<<<(N + 15) / 16, 256, 0, stream>>>(x, W1, dinv, u, N);
    scatter_bin_kernel<<<NB, 256, 0, stream>>>(packed, base, u, agg, N);
    finalize1_kernel<<<(N + 15) / 16, 256, 0, stream>>>(agg, u, dinv, b1, W2, N);

    scatter_bin_kernel<<<NB, 256, 0, stream>>>(packed, base, u, agg, N);
    finalize2_kernel<<<(N + 15) / 16, 256, 0, stream>>>(agg, u, dinv, b2, out, N);
}

// Round 5
// 801.922 us; speedup vs baseline: 1.1357x; 1.1357x over previous
//
#include <hip/hip_runtime.h>
#include <hip/hip_bf16.h>
#include <math.h>

// N = 100000, E = 3.2M, F_in = 128, H = C = 16. int inputs arrive as int32.
//
// out[d] = dinv[d]*(sum_{s->d} u[s] + u[d]) + b,  u = dinv .* (h @ W).
// R3: random f32 atomics run at ~300G/s (TCC RMW ceiling) -> 165us/scatter.
// R4: LDS-binned scatter with 782 blocks was latency-starved (22% occ, 3% VALU).
// R5: same binned design, but 4 segments/bucket (3128 blocks), 4x unrolled
//     gathers, and dense 8KB-tile atomic merge (6.4M atomics vs 51.2M).

#define F_IN 128
#define H 16
#define NPB 128            // nodes per bucket
#define MAX_NB 800         // max buckets (N <= 102400)
#define SEG 4              // segments per bucket

// ---- pass A: bucket histogram (LDS-privatized) ----
__global__ void hist_kernel(const int* __restrict__ dst, int* __restrict__ bcount, int E) {
    __shared__ int h[MAX_NB];
    for (int i = threadIdx.x; i < MAX_NB; i += blockDim.x) h[i] = 0;
    __syncthreads();
    int stride = gridDim.x * blockDim.x;
    for (int e = blockIdx.x * blockDim.x + threadIdx.x; e < E; e += stride)
        atomicAdd(&h[dst[e] >> 7], 1);
    __syncthreads();
    for (int i = threadIdx.x; i < MAX_NB; i += blockDim.x)
        if (h[i]) atomicAdd(&bcount[i], h[i]);
}

// ---- pass B: exclusive scan over NB buckets (single block) ----
__global__ void scan_kernel(const int* __restrict__ bcount, int* __restrict__ base,
                            int* __restrict__ cursor, int NB) {
    __shared__ int s[1024];
    int t = threadIdx.x;
    s[t] = (t < NB) ? bcount[t] : 0;
    __syncthreads();
    for (int off = 1; off < 1024; off <<= 1) {
        int v = (t >= off) ? s[t - off] : 0;
        __syncthreads();
        s[t] += v;
        __syncthreads();
    }
    if (t < NB) {
        int ex = (t == 0) ? 0 : s[t - 1];
        base[t] = ex;
        cursor[t] = ex;
        if (t == NB - 1) base[NB] = s[t];
    }
}

// ---- pass C: bin edges; packed = (dst&127)<<17 | src ----
__global__ void bin_kernel(const int* __restrict__ src, const int* __restrict__ dst,
                           int* __restrict__ cursor, unsigned* __restrict__ packed, int E) {
    __shared__ int h[MAX_NB];
    long long e0 = (long long)E * blockIdx.x / gridDim.x;
    long long e1 = (long long)E * (blockIdx.x + 1) / gridDim.x;
    for (int i = threadIdx.x; i < MAX_NB; i += blockDim.x) h[i] = 0;
    __syncthreads();
    for (long long e = e0 + threadIdx.x; e < e1; e += blockDim.x)
        atomicAdd(&h[dst[e] >> 7], 1);
    __syncthreads();
    for (int i = threadIdx.x; i < MAX_NB; i += blockDim.x) {
        int c = h[i];
        if (c) h[i] = atomicAdd(&cursor[i], c);
    }
    __syncthreads();
    for (long long e = e0 + threadIdx.x; e < e1; e += blockDim.x) {
        int d = dst[e];
        int b = d >> 7;
        int pos = atomicAdd(&h[b], 1);
        packed[pos] = (unsigned)src[e] | ((unsigned)(d & 127) << 17);
    }
}

// ---- degree + dinv from the binned list ----
__global__ void degdinv_kernel(const unsigned* __restrict__ packed, const int* __restrict__ base,
                               float* __restrict__ dinv, int N) {
    __shared__ int cnt[NPB];
    int b = blockIdx.x;
    if (threadIdx.x < NPB) cnt[threadIdx.x] = 0;
    __syncthreads();
    int e0 = base[b], e1 = base[b + 1];
    for (int i = e0 + threadIdx.x; i < e1; i += blockDim.x)
        atomicAdd(&cnt[packed[i] >> 17], 1);
    __syncthreads();
    if (threadIdx.x < NPB) {
        int node = b * NPB + threadIdx.x;
        if (node < N) dinv[node] = rsqrtf(1.0f + (float)cnt[threadIdx.x]);
    }
}

// ---- u[i][j] = dinv[i] * sum_k x[i][k]*W1[k][j]; x tile via LDS float4 ----
#define XPAD 132
__global__ void xw1_kernel(const float* __restrict__ x, const float* __restrict__ W1,
                           const float* __restrict__ dinv, float* __restrict__ u, int n) {
    __shared__ float sW1[F_IN * H];
    __shared__ float sx[16 * XPAD];
    for (int t = threadIdx.x; t < F_IN * H; t += blockDim.x) sW1[t] = W1[t];

    int basei = blockIdx.x * 16;
    for (int idx = threadIdx.x; idx < 512; idx += 256) {
        int r = idx >> 5;
        int kk = (idx & 31) << 2;
        int row = basei + r;
        float4 v = make_float4(0.f, 0.f, 0.f, 0.f);
        if (row < n) v = *(const float4*)(x + (size_t)row * F_IN + kk);
        *(float4*)(sx + r * XPAD + kk) = v;
    }
    __syncthreads();

    int r = threadIdx.x >> 4;
    int j = threadIdx.x & 15;
    int row = basei + r;
    if (row >= n) return;

    const float* xr = sx + r * XPAD;
    float acc = 0.0f;
#pragma unroll 16
    for (int k = 0; k < F_IN; k++) acc += xr[k] * sW1[k * H + j];
    u[(size_t)row * H + j] = dinv[row] * acc;
}

// ---- segmented binned scatter: gather u[src], LDS-accumulate, dense atomic merge ----
__global__ void scatter_seg_kernel(const unsigned* __restrict__ packed, const int* __restrict__ base,
                                   const float* __restrict__ u, float* __restrict__ agg, int N) {
    __shared__ float acc[NPB * H];   // 8 KB
    int b = blockIdx.x >> 2;         // bucket
    int seg = blockIdx.x & 3;        // segment within bucket
    for (int i = threadIdx.x; i < NPB * H; i += 256) acc[i] = 0.0f;
    __syncthreads();

    int e0 = base[b], e1 = base[b + 1];
    int len = e1 - e0;
    int s0 = e0 + (int)(((long long)len * seg) >> 2);
    int s1 = e0 + (int)(((long long)len * (seg + 1)) >> 2);

    int j = threadIdx.x & 15;
    int g = threadIdx.x >> 4;        // 16 edge-groups per block
    // 4x unrolled: 4 independent gathers in flight per lane
    for (int i = s0 + g; i < s1; i += 64) {
        int i1 = i + 16, i2 = i + 32, i3 = i + 48;
        unsigned p0 = packed[i];
        unsigned p1 = (i1 < s1) ? packed[i1] : 0;
        unsigned p2 = (i2 < s1) ? packed[i2] : 0;
        unsigned p3 = (i3 < s1) ? packed[i3] : 0;
        float v0 = u[(size_t)(p0 & 0x1FFFF) * H + j];
        float v1 = (i1 < s1) ? u[(size_t)(p1 & 0x1FFFF) * H + j] : 0.0f;
        float v2 = (i2 < s1) ? u[(size_t)(p2 & 0x1FFFF) * H + j] : 0.0f;
        float v3 = (i3 < s1) ? u[(size_t)(p3 & 0x1FFFF) * H + j] : 0.0f;
        atomicAdd(&acc[(p0 >> 17) * H + j], v0);
        if (i1 < s1) atomicAdd(&acc[(p1 >> 17) * H + j], v1);
        if (i2 < s1) atomicAdd(&acc[(p2 >> 17) * H + j], v2);
        if (i3 < s1) atomicAdd(&acc[(p3 >> 17) * H + j], v3);
    }
    __syncthreads();

    // dense coalesced atomic merge of the tile
    for (int i = threadIdx.x; i < NPB * H; i += 256) {
        int node = b * NPB + (i >> 4);
        if (node < N) atomicAdd(&agg[(size_t)node * H + (i & 15)], acc[i]);
    }
}

// ---- h1 = relu(dinv*(agg+u)+b1); u2 = dinv*(h1@W2) overwrites u ----
__global__ void finalize1_kernel(const float* __restrict__ agg, float* __restrict__ u,
                                 const float* __restrict__ dinv, const float* __restrict__ b1,
                                 const float* __restrict__ W2, int n) {
    __shared__ float sW2[H * H];
    __shared__ float sb1[H];
    if (threadIdx.x < H * H) sW2[threadIdx.x] = W2[threadIdx.x];
    if (threadIdx.x < H) sb1[threadIdx.x] = b1[threadIdx.x];
    __syncthreads();

    int row = blockIdx.x * 16 + (threadIdx.x >> 4);
    int j = threadIdx.x & 15;
    if (row >= n) return;

    float di = dinv[row];
    float h = di * (agg[(size_t)row * H + j] + u[(size_t)row * H + j]) + sb1[j];
    h = fmaxf(h, 0.0f);

    float acc = 0.0f;
#pragma unroll
    for (int k = 0; k < H; k++) {
        float hk = __shfl(h, k, 16);
        acc += hk * sW2[k * H + j];
    }
    u[(size_t)row * H + j] = di * acc;
}

// ---- v = dinv*(agg+u)+b2; out = log_softmax(v) ----
__global__ void finalize2_kernel(const float* __restrict__ agg, const float* __restrict__ u,
                                 const float* __restrict__ dinv, const float* __restrict__ b2,
                                 float* __restrict__ out, int n) {
    __shared__ float sb2[H];
    if (threadIdx.x < H) sb2[threadIdx.x] = b2[threadIdx.x];
    __syncthreads();

    int row = blockIdx.x * 16 + (threadIdx.x >> 4);
    int j = threadIdx.x & 15;
    if (row >= n) return;

    float di = dinv[row];
    float v = di * (agg[(size_t)row * H + j] + u[(size_t)row * H + j]) + sb2[j];

    float m = v;
#pragma unroll
    for (int off = 8; off >= 1; off >>= 1) m = fmaxf(m, __shfl_xor(m, off, 16));
    float ex = __expf(v - m);
    float s = ex;
#pragma unroll
    for (int off = 8; off >= 1; off >>= 1) s += __shfl_xor(s, off, 16);

    out[(size_t)row * H + j] = v - m - __logf(s);
}

extern "C" void kernel_launch(void* const* d_in, const int* in_sizes, int n_in,
                              void* d_out, int out_size, void* d_ws, size_t ws_size,
                              hipStream_t stream) {
    const float* x = (const float*)d_in[0];
    const int* edge_index = (const int*)d_in[1];
    const float* W1 = (const float*)d_in[2];
    const float* b1 = (const float*)d_in[3];
    const float* W2 = (const float*)d_in[4];
    const float* b2 = (const float*)d_in[5];
    float* out = (float*)d_out;

    const int N = in_sizes[0] / F_IN;        // 100000
    const int E = in_sizes[1] / 2;           // 3200000
    const int* src = edge_index;
    const int* dst = edge_index + E;
    const int NB = (N + NPB - 1) / NPB;      // 782

    // ws layout (4B units): dinv[N] | u[16N] | agg[16N] | packed[E] | bcount[NB] | base[NB+1] | cursor[NB]
    float* dinv = (float*)d_ws;
    float* u = dinv + N;
    float* agg = u + (size_t)N * H;
    unsigned* packed = (unsigned*)(agg + (size_t)N * H);
    int* bcount = (int*)(packed + E);
    int* base = bcount + NB;
    int* cursor = base + NB + 1;

    hipMemsetAsync(bcount, 0, NB * sizeof(int), stream);
    hipMemsetAsync(agg, 0, (size_t)N * H * sizeof(float), stream);

    hist_kernel<<<320, 256, 0, stream>>>(dst, bcount, E);
    scan_kernel<<<1, 1024, 0, stream>>>(bcount, base, cursor, NB);
    bin_kernel<<<320, 256, 0, stream>>>(src, dst, cursor, packed, E);
    degdinv_kernel<<<NB, 256, 0, stream>>>(packed, base, dinv, N);

    xw1_kernel<<<(N + 15) / 16, 256, 0, stream>>>(x, W1, dinv, u, N);
    scatter_seg_kernel<<<NB * SEG, 256, 0, stream>>>(packed, base, u, agg, N);
    finalize1_kernel<<<(N + 15) / 16, 256, 0, stream>>>(agg, u, dinv, b1, W2, N);

    hipMemsetAsync(agg, 0, (size_t)N * H * sizeof(float), stream);
    scatter_seg_kernel<<<NB * SEG, 256, 0, stream>>>(packed, base, u, agg, N);
    finalize2_kernel<<<(N + 15) / 16, 256, 0, stream>>>(agg, u, dinv, b2, out, N);
}

// Round 6
// 350.898 us; speedup vs baseline: 2.5955x; 2.2853x over previous
//
#include <hip/hip_runtime.h>
#include <hip/hip_bf16.h>
#include <math.h>

// N = 100000, E = 3.2M, F_in = 128, H = C = 16. int inputs arrive as int32.
//
// out[d] = dinv[d]*(sum_{s->d} u[s] + u[d]) + b,  u = dinv .* (h @ W).
// R3: global f32 atomics cap at ~19.5G transactions/s (165us / 3.2M-txn pass).
// R5: LDS f32 atomics ~3cy/lane -> 278us. Both pipes are dead ends.
// R6: zero hot-loop atomics. Bucket-bin -> per-bucket LDS counting sort -> CSR
//     (degrees fall out free). Aggregate = register-accumulated gather, one
//     wave per node, finalize fused (no agg buffer, no memsets of it).

#define F_IN 128
#define H 16
#define NPB 128            // nodes per bucket (binning/sort granularity)
#define MAX_NB 800         // max buckets (N <= 102400)
#define SMAX 4864          // max edges per bucket (mean 4096, +12 sigma)

// ---- pass A: bucket histogram (LDS-privatized) ----
__global__ void hist_kernel(const int* __restrict__ dst, int* __restrict__ bcount, int E) {
    __shared__ int h[MAX_NB];
    for (int i = threadIdx.x; i < MAX_NB; i += blockDim.x) h[i] = 0;
    __syncthreads();
    int stride = gridDim.x * blockDim.x;
    for (int e = blockIdx.x * blockDim.x + threadIdx.x; e < E; e += stride)
        atomicAdd(&h[dst[e] >> 7], 1);
    __syncthreads();
    for (int i = threadIdx.x; i < MAX_NB; i += blockDim.x)
        if (h[i]) atomicAdd(&bcount[i], h[i]);
}

// ---- pass B: exclusive scan over NB buckets (single block) ----
__global__ void scan_kernel(const int* __restrict__ bcount, int* __restrict__ base,
                            int* __restrict__ cursor, int NB) {
    __shared__ int s[1024];
    int t = threadIdx.x;
    s[t] = (t < NB) ? bcount[t] : 0;
    __syncthreads();
    for (int off = 1; off < 1024; off <<= 1) {
        int v = (t >= off) ? s[t - off] : 0;
        __syncthreads();
        s[t] += v;
        __syncthreads();
    }
    if (t < NB) {
        int ex = (t == 0) ? 0 : s[t - 1];
        base[t] = ex;
        cursor[t] = ex;
        if (t == NB - 1) base[NB] = s[t];
    }
}

// ---- pass C: bin edges into bucket regions; packed = (dst&127)<<17 | src ----
__global__ void bin_kernel(const int* __restrict__ src, const int* __restrict__ dst,
                           int* __restrict__ cursor, unsigned* __restrict__ packed, int E) {
    __shared__ int h[MAX_NB];
    long long e0 = (long long)E * blockIdx.x / gridDim.x;
    long long e1 = (long long)E * (blockIdx.x + 1) / gridDim.x;
    for (int i = threadIdx.x; i < MAX_NB; i += blockDim.x) h[i] = 0;
    __syncthreads();
    for (long long e = e0 + threadIdx.x; e < e1; e += blockDim.x)
        atomicAdd(&h[dst[e] >> 7], 1);
    __syncthreads();
    for (int i = threadIdx.x; i < MAX_NB; i += blockDim.x) {
        int c = h[i];
        if (c) h[i] = atomicAdd(&cursor[i], c);
    }
    __syncthreads();
    for (long long e = e0 + threadIdx.x; e < e1; e += blockDim.x) {
        int d = dst[e];
        int b = d >> 7;
        int pos = atomicAdd(&h[b], 1);
        packed[pos] = (unsigned)src[e] | ((unsigned)(d & 127) << 17);
    }
}

// ---- pass D: per-bucket LDS counting sort -> sorted[], rowptr[], dinv[] ----
__global__ void sortcsr_kernel(const unsigned* __restrict__ packed, const int* __restrict__ base,
                               unsigned* __restrict__ sorted, int* __restrict__ rowptr,
                               float* __restrict__ dinv, int N, int E) {
    __shared__ unsigned ssort[SMAX];
    __shared__ int cnt[NPB], offs[NPB], cur[NPB];
    int b = blockIdx.x;
    int e0 = base[b];
    int len = base[b + 1] - e0;
    if (len > SMAX) len = SMAX;   // p ~ 0 safeguard

    for (int i = threadIdx.x; i < NPB; i += 256) cnt[i] = 0;
    __syncthreads();
    for (int i = threadIdx.x; i < len; i += 256)
        atomicAdd(&cnt[packed[e0 + i] >> 17], 1);
    __syncthreads();
    // inclusive scan over 128 counters (Hillis-Steele)
    if (threadIdx.x < NPB) offs[threadIdx.x] = cnt[threadIdx.x];
    __syncthreads();
    for (int off = 1; off < NPB; off <<= 1) {
        int v = 0;
        if (threadIdx.x < NPB && threadIdx.x >= off) v = offs[threadIdx.x - off];
        __syncthreads();
        if (threadIdx.x < NPB) offs[threadIdx.x] += v;
        __syncthreads();
    }
    if (threadIdx.x < NPB) {
        int ex = offs[threadIdx.x] - cnt[threadIdx.x];   // exclusive
        cur[threadIdx.x] = ex;
        int node = b * NPB + threadIdx.x;
        if (node < N) {
            rowptr[node] = e0 + ex;
            dinv[node] = rsqrtf(1.0f + (float)cnt[threadIdx.x]);
        }
    }
    __syncthreads();
    for (int i = threadIdx.x; i < len; i += 256) {
        unsigned p = packed[e0 + i];
        int pos = atomicAdd(&cur[p >> 17], 1);
        ssort[pos] = p;
    }
    __syncthreads();
    for (int i = threadIdx.x; i < len; i += 256) sorted[e0 + i] = ssort[i];
    if (b == 0 && threadIdx.x == 0) rowptr[N] = E;
}

// ---- u[i][j] = dinv[i] * sum_k x[i][k]*W1[k][j]; x tile via LDS float4 ----
#define XPAD 132
__global__ void xw1_kernel(const float* __restrict__ x, const float* __restrict__ W1,
                           const float* __restrict__ dinv, float* __restrict__ u, int n) {
    __shared__ float sW1[F_IN * H];
    __shared__ float sx[16 * XPAD];
    for (int t = threadIdx.x; t < F_IN * H; t += blockDim.x) sW1[t] = W1[t];

    int basei = blockIdx.x * 16;
    for (int idx = threadIdx.x; idx < 512; idx += 256) {
        int r = idx >> 5;
        int kk = (idx & 31) << 2;
        int row = basei + r;
        float4 v = make_float4(0.f, 0.f, 0.f, 0.f);
        if (row < n) v = *(const float4*)(x + (size_t)row * F_IN + kk);
        *(float4*)(sx + r * XPAD + kk) = v;
    }
    __syncthreads();

    int r = threadIdx.x >> 4;
    int j = threadIdx.x & 15;
    int row = basei + r;
    if (row >= n) return;

    const float* xr = sx + r * XPAD;
    float acc = 0.0f;
#pragma unroll 16
    for (int k = 0; k < F_IN; k++) acc += xr[k] * sW1[k * H + j];
    u[(size_t)row * H + j] = dinv[row] * acc;
}

// ---- layer-1 gather + finalize: one wave per node (4 edges x 16 ch/iter),
//      register accumulate, shfl reduce, then fused relu + @W2 -> u2 ----
__global__ void gatherfin1_kernel(const unsigned* __restrict__ sorted, const int* __restrict__ rowptr,
                                  const float* __restrict__ u, const float* __restrict__ dinv,
                                  const float* __restrict__ b1, const float* __restrict__ W2,
                                  float* __restrict__ u2, int N) {
    __shared__ float tile[64 * 16];
    __shared__ float sW2[256];
    __shared__ float sb1[16];
    sW2[threadIdx.x] = W2[threadIdx.x];
    if (threadIdx.x < 16) sb1[threadIdx.x] = b1[threadIdx.x];

    int lane = threadIdx.x & 63;
    int wave = threadIdx.x >> 6;          // 0..3
    int j = lane & 15, g = lane >> 4;     // channel, edge-slot
    int nodeBase = blockIdx.x * 64 + wave * 16;

    for (int t = 0; t < 16; t++) {
        int node = nodeBase + t;
        float acc = 0.0f;
        if (node < N) {
            int r0 = rowptr[node], r1 = rowptr[node + 1];
            int k = r0 + g;
            for (; k + 4 < r1; k += 8) {      // 2 independent lines in flight
                unsigned pa = sorted[k], pb = sorted[k + 4];
                acc += u[(size_t)(pa & 0x1FFFF) * H + j];
                acc += u[(size_t)(pb & 0x1FFFF) * H + j];
            }
            if (k < r1) acc += u[(size_t)(sorted[k] & 0x1FFFF) * H + j];
        }
        acc += __shfl_xor(acc, 16);
        acc += __shfl_xor(acc, 32);
        if (lane < 16) tile[(wave * 16 + t) * 16 + j] = acc;
    }
    __syncthreads();

    int jj = threadIdx.x & 15;
    for (int rr = 0; rr < 4; rr++) {
        int rl = (threadIdx.x >> 4) + rr * 16;       // 0..63
        int node = blockIdx.x * 64 + rl;
        float h = 0.f, di = 0.f;
        if (node < N) {
            di = dinv[node];
            h = di * (tile[rl * 16 + jj] + u[(size_t)node * H + jj]) + sb1[jj];
            h = fmaxf(h, 0.f);
        }
        float acc2 = 0.f;
#pragma unroll
        for (int kk = 0; kk < 16; kk++) {
            float hk = __shfl(h, kk, 16);
            acc2 += hk * sW2[kk * 16 + jj];
        }
        if (node < N) u2[(size_t)node * H + jj] = di * acc2;
    }
}

// ---- layer-2 gather + finalize: log_softmax -> out ----
__global__ void gatherfin2_kernel(const unsigned* __restrict__ sorted, const int* __restrict__ rowptr,
                                  const float* __restrict__ u2, const float* __restrict__ dinv,
                                  const float* __restrict__ b2, float* __restrict__ out, int N) {
    __shared__ float tile[64 * 16];
    __shared__ float sb2[16];
    if (threadIdx.x < 16) sb2[threadIdx.x] = b2[threadIdx.x];

    int lane = threadIdx.x & 63;
    int wave = threadIdx.x >> 6;
    int j = lane & 15, g = lane >> 4;
    int nodeBase = blockIdx.x * 64 + wave * 16;

    for (int t = 0; t < 16; t++) {
        int node = nodeBase + t;
        float acc = 0.0f;
        if (node < N) {
            int r0 = rowptr[node], r1 = rowptr[node + 1];
            int k = r0 + g;
            for (; k + 4 < r1; k += 8) {
                unsigned pa = sorted[k], pb = sorted[k + 4];
                acc += u2[(size_t)(pa & 0x1FFFF) * H + j];
                acc += u2[(size_t)(pb & 0x1FFFF) * H + j];
            }
            if (k < r1) acc += u2[(size_t)(sorted[k] & 0x1FFFF) * H + j];
        }
        acc += __shfl_xor(acc, 16);
        acc += __shfl_xor(acc, 32);
        if (lane < 16) tile[(wave * 16 + t) * 16 + j] = acc;
    }
    __syncthreads();

    int jj = threadIdx.x & 15;
    for (int rr = 0; rr < 4; rr++) {
        int rl = (threadIdx.x >> 4) + rr * 16;
        int node = blockIdx.x * 64 + rl;
        if (node >= N) continue;
        float di = dinv[node];
        float v = di * (tile[rl * 16 + jj] + u2[(size_t)node * H + jj]) + sb2[jj];

        float m = v;
#pragma unroll
        for (int off = 8; off >= 1; off >>= 1) m = fmaxf(m, __shfl_xor(m, off, 16));
        float ex = __expf(v - m);
        float s = ex;
#pragma unroll
        for (int off = 8; off >= 1; off >>= 1) s += __shfl_xor(s, off, 16);

        out[(size_t)node * H + jj] = v - m - __logf(s);
    }
}

extern "C" void kernel_launch(void* const* d_in, const int* in_sizes, int n_in,
                              void* d_out, int out_size, void* d_ws, size_t ws_size,
                              hipStream_t stream) {
    const float* x = (const float*)d_in[0];
    const int* edge_index = (const int*)d_in[1];
    const float* W1 = (const float*)d_in[2];
    const float* b1 = (const float*)d_in[3];
    const float* W2 = (const float*)d_in[4];
    const float* b2 = (const float*)d_in[5];
    float* out = (float*)d_out;

    const int N = in_sizes[0] / F_IN;        // 100000
    const int E = in_sizes[1] / 2;           // 3200000
    const int* src = edge_index;
    const int* dst = edge_index + E;
    const int NB = (N + NPB - 1) / NPB;      // 782

    // ws (4B units): dinv[N] | u[16N] | u2[16N] | packed[E] | sorted[E] |
    //                rowptr[N+1] | bcount[NB] | base[NB+1] | cursor[NB]
    float* dinv = (float*)d_ws;
    float* u = dinv + N;
    float* u2 = u + (size_t)N * H;
    unsigned* packed = (unsigned*)(u2 + (size_t)N * H);
    unsigned* sorted = packed + E;
    int* rowptr = (int*)(sorted + E);
    int* bcount = rowptr + N + 1;
    int* base = bcount + NB;
    int* cursor = base + NB + 1;

    hipMemsetAsync(bcount, 0, NB * sizeof(int), stream);

    hist_kernel<<<320, 256, 0, stream>>>(dst, bcount, E);
    scan_kernel<<<1, 1024, 0, stream>>>(bcount, base, cursor, NB);
    bin_kernel<<<320, 256, 0, stream>>>(src, dst, cursor, packed, E);
    sortcsr_kernel<<<NB, 256, 0, stream>>>(packed, base, sorted, rowptr, dinv, N, E);

    xw1_kernel<<<(N + 15) / 16, 256, 0, stream>>>(x, W1, dinv, u, N);
    gatherfin1_kernel<<<(N + 63) / 64, 256, 0, stream>>>(sorted, rowptr, u, dinv, b1, W2, u2, N);
    gatherfin2_kernel<<<(N + 63) / 64, 256, 0, stream>>>(sorted, rowptr, u2, dinv, b2, out, N);
}

// Round 7
// 312.960 us; speedup vs baseline: 2.9102x; 1.1212x over previous
//
#include <hip/hip_runtime.h>
#include <hip/hip_bf16.h>
#include <math.h>

// N = 100000, E = 3.2M, F_in = 128, H = C = 16. int inputs arrive as int32.
//
// out[d] = dinv[d]*(sum_{s->d} u[s] + u[d]) + b,  u = dinv .* (h @ W).
// R3: global f32 atomics ~19.5G txn/s. R5: LDS f32 atomics ~3cy/lane.
// R6: sort->CSR->register gather = 351us. Now: bin was 10% occupancy w/
//     contended cursors; gathers thrash L2 (u = 6.4MB f32 > 4MiB/XCD).
// R7: deterministic 2-pass radix binning (1024 blocks, no global atomics),
//     and bf16 u/u2 so the message array (3.2MB) fits per-XCD L2.

#define F_IN 128
#define H 16
#define NPB 128            // nodes per bucket
#define MAX_NB 800         // max buckets (N <= 102400)
#define NBLK 1024          // binning blocks
#define SMAX 4864          // max edges per bucket (mean 4096, +12 sigma)

typedef __hip_bfloat16 bf16;

// ---- pass A: per-block bucket histogram -> hist_t[bucket*NBLK + block] ----
__global__ void histA_kernel(const int* __restrict__ dst, int* __restrict__ hist_t,
                             int E, int NB) {
    __shared__ int h[MAX_NB];
    int b = blockIdx.x;
    long long e0 = (long long)E * b / NBLK;
    long long e1 = (long long)E * (b + 1) / NBLK;
    for (int i = threadIdx.x; i < NB; i += 256) h[i] = 0;
    __syncthreads();
    for (long long e = e0 + threadIdx.x; e < e1; e += 256)
        atomicAdd(&h[dst[e] >> 7], 1);
    __syncthreads();
    for (int i = threadIdx.x; i < NB; i += 256) hist_t[i * NBLK + b] = h[i];
}

// ---- pass B1: per-bucket column scan (exclusive over blocks) + bucket totals ----
__global__ void colscan_kernel(int* __restrict__ hist_t, int* __restrict__ btot) {
    __shared__ int s[NBLK];
    int j = blockIdx.x;
    int t = threadIdx.x;
    int v = hist_t[j * NBLK + t];
    s[t] = v;
    __syncthreads();
    for (int off = 1; off < NBLK; off <<= 1) {
        int w = (t >= off) ? s[t - off] : 0;
        __syncthreads();
        s[t] += w;
        __syncthreads();
    }
    hist_t[j * NBLK + t] = s[t] - v;          // exclusive prefix within bucket
    if (t == NBLK - 1) btot[j] = s[t];
}

// ---- pass B2: exclusive scan over bucket totals -> base[] ----
__global__ void bucketscan_kernel(const int* __restrict__ btot, int* __restrict__ base, int NB) {
    __shared__ int s[1024];
    int t = threadIdx.x;
    s[t] = (t < NB) ? btot[t] : 0;
    __syncthreads();
    for (int off = 1; off < 1024; off <<= 1) {
        int v = (t >= off) ? s[t - off] : 0;
        __syncthreads();
        s[t] += v;
        __syncthreads();
    }
    if (t < NB) base[t] = s[t] - btot[t];
    if (t == NB - 1) base[NB] = s[t];
}

// ---- pass C: place edges; packed = (dst&127)<<17 | src; LDS cursors only ----
__global__ void binC_kernel(const int* __restrict__ src, const int* __restrict__ dst,
                            const int* __restrict__ hist_t, const int* __restrict__ base,
                            unsigned* __restrict__ packed, int E, int NB) {
    __shared__ int pos[MAX_NB];
    int b = blockIdx.x;
    long long e0 = (long long)E * b / NBLK;
    long long e1 = (long long)E * (b + 1) / NBLK;
    for (int i = threadIdx.x; i < NB; i += 256)
        pos[i] = base[i] + hist_t[i * NBLK + b];
    __syncthreads();
    for (long long e = e0 + threadIdx.x; e < e1; e += 256) {
        int d = dst[e];
        int bk = d >> 7;
        int p = atomicAdd(&pos[bk], 1);
        packed[p] = (unsigned)src[e] | ((unsigned)(d & 127) << 17);
    }
}

// ---- pass D: per-bucket LDS counting sort -> sorted[], rowptr[], dinv[] ----
__global__ void sortcsr_kernel(const unsigned* __restrict__ packed, const int* __restrict__ base,
                               unsigned* __restrict__ sorted, int* __restrict__ rowptr,
                               float* __restrict__ dinv, int N, int E) {
    __shared__ unsigned ssort[SMAX];
    __shared__ int cnt[NPB], offs[NPB], cur[NPB];
    int b = blockIdx.x;
    int e0 = base[b];
    int len = base[b + 1] - e0;
    if (len > SMAX) len = SMAX;

    for (int i = threadIdx.x; i < NPB; i += 256) cnt[i] = 0;
    __syncthreads();
    for (int i = threadIdx.x; i < len; i += 256)
        atomicAdd(&cnt[packed[e0 + i] >> 17], 1);
    __syncthreads();
    if (threadIdx.x < NPB) offs[threadIdx.x] = cnt[threadIdx.x];
    __syncthreads();
    for (int off = 1; off < NPB; off <<= 1) {
        int v = 0;
        if (threadIdx.x < NPB && threadIdx.x >= off) v = offs[threadIdx.x - off];
        __syncthreads();
        if (threadIdx.x < NPB) offs[threadIdx.x] += v;
        __syncthreads();
    }
    if (threadIdx.x < NPB) {
        int ex = offs[threadIdx.x] - cnt[threadIdx.x];
        cur[threadIdx.x] = ex;
        int node = b * NPB + threadIdx.x;
        if (node < N) {
            rowptr[node] = e0 + ex;
            dinv[node] = rsqrtf(1.0f + (float)cnt[threadIdx.x]);
        }
    }
    __syncthreads();
    for (int i = threadIdx.x; i < len; i += 256) {
        unsigned p = packed[e0 + i];
        int pos = atomicAdd(&cur[p >> 17], 1);
        ssort[pos] = p;
    }
    __syncthreads();
    for (int i = threadIdx.x; i < len; i += 256) sorted[e0 + i] = ssort[i];
    if (b == 0 && threadIdx.x == 0) rowptr[N] = E;
}

// ---- u[i][j] = dinv[i] * sum_k x[i][k]*W1[k][j]  (bf16 out) ----
#define XPAD 132
__global__ void xw1_kernel(const float* __restrict__ x, const float* __restrict__ W1,
                           const float* __restrict__ dinv, bf16* __restrict__ u, int n) {
    __shared__ float sW1[F_IN * H];
    __shared__ float sx[16 * XPAD];
    for (int t = threadIdx.x; t < F_IN * H; t += blockDim.x) sW1[t] = W1[t];

    int basei = blockIdx.x * 16;
    for (int idx = threadIdx.x; idx < 512; idx += 256) {
        int r = idx >> 5;
        int kk = (idx & 31) << 2;
        int row = basei + r;
        float4 v = make_float4(0.f, 0.f, 0.f, 0.f);
        if (row < n) v = *(const float4*)(x + (size_t)row * F_IN + kk);
        *(float4*)(sx + r * XPAD + kk) = v;
    }
    __syncthreads();

    int r = threadIdx.x >> 4;
    int j = threadIdx.x & 15;
    int row = basei + r;
    if (row >= n) return;

    const float* xr = sx + r * XPAD;
    float acc = 0.0f;
#pragma unroll 16
    for (int k = 0; k < F_IN; k++) acc += xr[k] * sW1[k * H + j];
    u[(size_t)row * H + j] = __float2bfloat16(dinv[row] * acc);
}

// ---- layer-1 gather + finalize (bf16 in, bf16 out) ----
__global__ void gatherfin1_kernel(const unsigned* __restrict__ sorted, const int* __restrict__ rowptr,
                                  const bf16* __restrict__ u, const float* __restrict__ dinv,
                                  const float* __restrict__ b1, const float* __restrict__ W2,
                                  bf16* __restrict__ u2, int N) {
    __shared__ float tile[64 * 16];
    __shared__ float sW2[256];
    __shared__ float sb1[16];
    sW2[threadIdx.x] = W2[threadIdx.x];
    if (threadIdx.x < 16) sb1[threadIdx.x] = b1[threadIdx.x];

    int lane = threadIdx.x & 63;
    int wave = threadIdx.x >> 6;
    int j = lane & 15, g = lane >> 4;
    int nodeBase = blockIdx.x * 64 + wave * 16;

    for (int t = 0; t < 16; t++) {
        int node = nodeBase + t;
        float acc = 0.0f;
        if (node < N) {
            int r0 = rowptr[node], r1 = rowptr[node + 1];
            int k = r0 + g;
            for (; k + 4 < r1; k += 8) {
                unsigned pa = sorted[k], pb = sorted[k + 4];
                acc += __bfloat162float(u[(size_t)(pa & 0x1FFFF) * H + j]);
                acc += __bfloat162float(u[(size_t)(pb & 0x1FFFF) * H + j]);
            }
            if (k < r1) acc += __bfloat162float(u[(size_t)(sorted[k] & 0x1FFFF) * H + j]);
        }
        acc += __shfl_xor(acc, 16);
        acc += __shfl_xor(acc, 32);
        if (lane < 16) tile[(wave * 16 + t) * 16 + j] = acc;
    }
    __syncthreads();

    int jj = threadIdx.x & 15;
    for (int rr = 0; rr < 4; rr++) {
        int rl = (threadIdx.x >> 4) + rr * 16;
        int node = blockIdx.x * 64 + rl;
        float h = 0.f, di = 0.f;
        if (node < N) {
            di = dinv[node];
            h = di * (tile[rl * 16 + jj] + __bfloat162float(u[(size_t)node * H + jj])) + sb1[jj];
            h = fmaxf(h, 0.f);
        }
        float acc2 = 0.f;
#pragma unroll
        for (int kk = 0; kk < 16; kk++) {
            float hk = __shfl(h, kk, 16);
            acc2 += hk * sW2[kk * 16 + jj];
        }
        if (node < N) u2[(size_t)node * H + jj] = __float2bfloat16(di * acc2);
    }
}

// ---- layer-2 gather + finalize: log_softmax -> out (f32) ----
__global__ void gatherfin2_kernel(const unsigned* __restrict__ sorted, const int* __restrict__ rowptr,
                                  const bf16* __restrict__ u2, const float* __restrict__ dinv,
                                  const float* __restrict__ b2, float* __restrict__ out, int N) {
    __shared__ float tile[64 * 16];
    __shared__ float sb2[16];
    if (threadIdx.x < 16) sb2[threadIdx.x] = b2[threadIdx.x];

    int lane = threadIdx.x & 63;
    int wave = threadIdx.x >> 6;
    int j = lane & 15, g = lane >> 4;
    int nodeBase = blockIdx.x * 64 + wave * 16;

    for (int t = 0; t < 16; t++) {
        int node = nodeBase + t;
        float acc = 0.0f;
        if (node < N) {
            int r0 = rowptr[node], r1 = rowptr[node + 1];
            int k = r0 + g;
            for (; k + 4 < r1; k += 8) {
                unsigned pa = sorted[k], pb = sorted[k + 4];
                acc += __bfloat162float(u2[(size_t)(pa & 0x1FFFF) * H + j]);
                acc += __bfloat162float(u2[(size_t)(pb & 0x1FFFF) * H + j]);
            }
            if (k < r1) acc += __bfloat162float(u2[(size_t)(sorted[k] & 0x1FFFF) * H + j]);
        }
        acc += __shfl_xor(acc, 16);
        acc += __shfl_xor(acc, 32);
        if (lane < 16) tile[(wave * 16 + t) * 16 + j] = acc;
    }
    __syncthreads();

    int jj = threadIdx.x & 15;
    for (int rr = 0; rr < 4; rr++) {
        int rl = (threadIdx.x >> 4) + rr * 16;
        int node = blockIdx.x * 64 + rl;
        if (node >= N) continue;
        float di = dinv[node];
        float v = di * (tile[rl * 16 + jj] + __bfloat162float(u2[(size_t)node * H + jj])) + sb2[jj];

        float m = v;
#pragma unroll
        for (int off = 8; off >= 1; off >>= 1) m = fmaxf(m, __shfl_xor(m, off, 16));
        float ex = __expf(v - m);
        float s = ex;
#pragma unroll
        for (int off = 8; off >= 1; off >>= 1) s += __shfl_xor(s, off, 16);

        out[(size_t)node * H + jj] = v - m - __logf(s);
    }
}

extern "C" void kernel_launch(void* const* d_in, const int* in_sizes, int n_in,
                              void* d_out, int out_size, void* d_ws, size_t ws_size,
                              hipStream_t stream) {
    const float* x = (const float*)d_in[0];
    const int* edge_index = (const int*)d_in[1];
    const float* W1 = (const float*)d_in[2];
    const float* b1 = (const float*)d_in[3];
    const float* W2 = (const float*)d_in[4];
    const float* b2 = (const float*)d_in[5];
    float* out = (float*)d_out;

    const int N = in_sizes[0] / F_IN;        // 100000
    const int E = in_sizes[1] / 2;           // 3200000
    const int* src = edge_index;
    const int* dst = edge_index + E;
    const int NB = (N + NPB - 1) / NPB;      // 782

    // ws (4B units): dinv[N] | u[16N bf16 = 8N] | u2[8N] | packed[E] | sorted[E] |
    //                hist_t[MAX_NB*NBLK] | rowptr[N+1] | btot[NB] | base[NB+1]
    float* dinv = (float*)d_ws;
    bf16* u = (bf16*)(dinv + N);
    bf16* u2 = (bf16*)((unsigned*)u + (size_t)N * H / 2);
    unsigned* packed = (unsigned*)((unsigned*)u2 + (size_t)N * H / 2);
    unsigned* sorted = packed + E;
    int* hist_t = (int*)(sorted + E);
    int* rowptr = hist_t + (size_t)MAX_NB * NBLK;
    int* btot = rowptr + N + 1;
    int* base = btot + NB;

    histA_kernel<<<NBLK, 256, 0, stream>>>(dst, hist_t, E, NB);
    colscan_kernel<<<NB, NBLK, 0, stream>>>(hist_t, btot);
    bucketscan_kernel<<<1, 1024, 0, stream>>>(btot, base, NB);
    binC_kernel<<<NBLK, 256, 0, stream>>>(src, dst, hist_t, base, packed, E, NB);
    sortcsr_kernel<<<NB, 256, 0, stream>>>(packed, base, sorted, rowptr, dinv, N, E);

    xw1_kernel<<<(N + 15) / 16, 256, 0, stream>>>(x, W1, dinv, u, N);
    gatherfin1_kernel<<<(N + 63) / 64, 256, 0, stream>>>(sorted, rowptr, u, dinv, b1, W2, u2, N);
    gatherfin2_kernel<<<(N + 63) / 64, 256, 0, stream>>>(sorted, rowptr, u2, dinv, b2, out, N);
}

// Round 8
// 271.409 us; speedup vs baseline: 3.3557x; 1.1531x over previous
//
#include <hip/hip_runtime.h>
#include <hip/hip_bf16.h>
#include <math.h>

// N = 100000, E = 3.2M, F_in = 128, H = C = 16. int inputs arrive as int32.
//
// out[d] = dinv[d]*(sum_{s->d} u[s] + u[d]) + b,  u = dinv .* (h @ W).
// R3: global f32 atomics ~19.5G txn/s. R5: LDS f32 atomics ~3cy/lane.
// R6: sort->CSR->register gather. R7: bf16 messages (L2-resident) = 313us.
// R8: binC write-allocate fix (256 blocks x 1024 thr -> 64B runs/bucket) and
//     bf16x2 gather lanes (16 row-gathers in flight/wave, half the issues).

#define F_IN 128
#define H 16
#define NPB 128            // nodes per bucket
#define MAX_NB 800         // max buckets (N <= 102400)
#define NBLK 256           // binning blocks (must match hist partition)
#define BINT 1024          // binning threads per block
#define SMAX 4864          // max edges per bucket (mean 4096, +12 sigma)

typedef __hip_bfloat16 bf16;

__device__ __forceinline__ float bflo(unsigned v) { return __uint_as_float(v << 16); }
__device__ __forceinline__ float bfhi(unsigned v) { return __uint_as_float(v & 0xffff0000u); }

// ---- pass A: per-block bucket histogram -> hist_t[bucket*NBLK + block] ----
__global__ void histA_kernel(const int* __restrict__ dst, int* __restrict__ hist_t,
                             int E, int NB) {
    __shared__ int h[MAX_NB];
    int b = blockIdx.x;
    long long e0 = (long long)E * b / NBLK;
    long long e1 = (long long)E * (b + 1) / NBLK;
    for (int i = threadIdx.x; i < NB; i += BINT) h[i] = 0;
    __syncthreads();
    for (long long e = e0 + threadIdx.x; e < e1; e += BINT)
        atomicAdd(&h[dst[e] >> 7], 1);
    __syncthreads();
    for (int i = threadIdx.x; i < NB; i += BINT) hist_t[i * NBLK + b] = h[i];
}

// ---- pass B1: per-bucket exclusive scan over blocks + bucket totals ----
__global__ void colscan_kernel(int* __restrict__ hist_t, int* __restrict__ btot) {
    __shared__ int s[NBLK];
    int j = blockIdx.x;
    int t = threadIdx.x;
    int v = hist_t[j * NBLK + t];
    s[t] = v;
    __syncthreads();
    for (int off = 1; off < NBLK; off <<= 1) {
        int w = (t >= off) ? s[t - off] : 0;
        __syncthreads();
        s[t] += w;
        __syncthreads();
    }
    hist_t[j * NBLK + t] = s[t] - v;
    if (t == NBLK - 1) btot[j] = s[t];
}

// ---- pass B2: exclusive scan over bucket totals -> base[] ----
__global__ void bucketscan_kernel(const int* __restrict__ btot, int* __restrict__ base, int NB) {
    __shared__ int s[1024];
    int t = threadIdx.x;
    s[t] = (t < NB) ? btot[t] : 0;
    __syncthreads();
    for (int off = 1; off < 1024; off <<= 1) {
        int v = (t >= off) ? s[t - off] : 0;
        __syncthreads();
        s[t] += v;
        __syncthreads();
    }
    if (t < NB) base[t] = s[t] - btot[t];
    if (t == NB - 1) base[NB] = s[t];
}

// ---- pass C: place edges; packed = (dst&127)<<17 | src; LDS cursors only ----
__global__ void binC_kernel(const int* __restrict__ src, const int* __restrict__ dst,
                            const int* __restrict__ hist_t, const int* __restrict__ base,
                            unsigned* __restrict__ packed, int E, int NB) {
    __shared__ int pos[MAX_NB];
    int b = blockIdx.x;
    long long e0 = (long long)E * b / NBLK;
    long long e1 = (long long)E * (b + 1) / NBLK;
    for (int i = threadIdx.x; i < NB; i += BINT)
        pos[i] = base[i] + hist_t[i * NBLK + b];
    __syncthreads();
    for (long long e = e0 + threadIdx.x; e < e1; e += BINT) {
        int d = dst[e];
        int bk = d >> 7;
        int p = atomicAdd(&pos[bk], 1);
        packed[p] = (unsigned)src[e] | ((unsigned)(d & 127) << 17);
    }
}

// ---- pass D: per-bucket LDS counting sort -> sorted[], rowptr[], dinv[] ----
__global__ void sortcsr_kernel(const unsigned* __restrict__ packed, const int* __restrict__ base,
                               unsigned* __restrict__ sorted, int* __restrict__ rowptr,
                               float* __restrict__ dinv, int N, int E) {
    __shared__ unsigned ssort[SMAX];
    __shared__ int cnt[NPB], offs[NPB], cur[NPB];
    int b = blockIdx.x;
    int e0 = base[b];
    int len = base[b + 1] - e0;
    if (len > SMAX) len = SMAX;

    for (int i = threadIdx.x; i < NPB; i += 256) cnt[i] = 0;
    __syncthreads();
    for (int i = threadIdx.x; i < len; i += 256)
        atomicAdd(&cnt[packed[e0 + i] >> 17], 1);
    __syncthreads();
    if (threadIdx.x < NPB) offs[threadIdx.x] = cnt[threadIdx.x];
    __syncthreads();
    for (int off = 1; off < NPB; off <<= 1) {
        int v = 0;
        if (threadIdx.x < NPB && threadIdx.x >= off) v = offs[threadIdx.x - off];
        __syncthreads();
        if (threadIdx.x < NPB) offs[threadIdx.x] += v;
        __syncthreads();
    }
    if (threadIdx.x < NPB) {
        int ex = offs[threadIdx.x] - cnt[threadIdx.x];
        cur[threadIdx.x] = ex;
        int node = b * NPB + threadIdx.x;
        if (node < N) {
            rowptr[node] = e0 + ex;
            dinv[node] = rsqrtf(1.0f + (float)cnt[threadIdx.x]);
        }
    }
    __syncthreads();
    for (int i = threadIdx.x; i < len; i += 256) {
        unsigned p = packed[e0 + i];
        int pos = atomicAdd(&cur[p >> 17], 1);
        ssort[pos] = p;
    }
    __syncthreads();
    for (int i = threadIdx.x; i < len; i += 256) sorted[e0 + i] = ssort[i];
    if (b == 0 && threadIdx.x == 0) rowptr[N] = E;
}

// ---- u[i][j] = dinv[i] * sum_k x[i][k]*W1[k][j]  (bf16 out) ----
#define XPAD 132
__global__ void xw1_kernel(const float* __restrict__ x, const float* __restrict__ W1,
                           const float* __restrict__ dinv, bf16* __restrict__ u, int n) {
    __shared__ float sW1[F_IN * H];
    __shared__ float sx[16 * XPAD];
    for (int t = threadIdx.x; t < F_IN * H; t += blockDim.x) sW1[t] = W1[t];

    int basei = blockIdx.x * 16;
    for (int idx = threadIdx.x; idx < 512; idx += 256) {
        int r = idx >> 5;
        int kk = (idx & 31) << 2;
        int row = basei + r;
        float4 v = make_float4(0.f, 0.f, 0.f, 0.f);
        if (row < n) v = *(const float4*)(x + (size_t)row * F_IN + kk);
        *(float4*)(sx + r * XPAD + kk) = v;
    }
    __syncthreads();

    int r = threadIdx.x >> 4;
    int j = threadIdx.x & 15;
    int row = basei + r;
    if (row >= n) return;

    const float* xr = sx + r * XPAD;
    float acc = 0.0f;
#pragma unroll 16
    for (int k = 0; k < F_IN; k++) acc += xr[k] * sW1[k * H + j];
    u[(size_t)row * H + j] = __float2bfloat16(dinv[row] * acc);
}

// ---- layer-1 gather + finalize: lane = (ch-pair 0..7) x (slot 0..7),
//      16 row-gathers in flight per wave ----
__global__ void gatherfin1_kernel(const unsigned* __restrict__ sorted, const int* __restrict__ rowptr,
                                  const bf16* __restrict__ u, const float* __restrict__ dinv,
                                  const float* __restrict__ b1, const float* __restrict__ W2,
                                  bf16* __restrict__ u2, int N) {
    __shared__ float tile[64 * 16];
    __shared__ float sW2[256];
    __shared__ float sb1[16];
    sW2[threadIdx.x] = W2[threadIdx.x];
    if (threadIdx.x < 16) sb1[threadIdx.x] = b1[threadIdx.x];

    const unsigned* uv = (const unsigned*)u;   // [node*8 + j2] channel pairs
    int lane = threadIdx.x & 63;
    int wave = threadIdx.x >> 6;
    int j2 = lane & 7, g = lane >> 3;
    int nodeBase = blockIdx.x * 64 + wave * 16;

    for (int t = 0; t < 16; t++) {
        int node = nodeBase + t;
        float ax = 0.f, ay = 0.f;
        if (node < N) {
            int r0 = rowptr[node], r1 = rowptr[node + 1];
            int k = r0 + g;
            for (; k + 8 < r1; k += 16) {
                unsigned pa = sorted[k], pb = sorted[k + 8];
                unsigned va = uv[(size_t)(pa & 0x1FFFF) * 8 + j2];
                unsigned vb = uv[(size_t)(pb & 0x1FFFF) * 8 + j2];
                ax += bflo(va) + bflo(vb);
                ay += bfhi(va) + bfhi(vb);
            }
            if (k < r1) {
                unsigned va = uv[(size_t)(sorted[k] & 0x1FFFF) * 8 + j2];
                ax += bflo(va);
                ay += bfhi(va);
            }
        }
        ax += __shfl_xor(ax, 8);  ay += __shfl_xor(ay, 8);
        ax += __shfl_xor(ax, 16); ay += __shfl_xor(ay, 16);
        ax += __shfl_xor(ax, 32); ay += __shfl_xor(ay, 32);
        if (g == 0) {
            tile[(wave * 16 + t) * 16 + 2 * j2] = ax;
            tile[(wave * 16 + t) * 16 + 2 * j2 + 1] = ay;
        }
    }
    __syncthreads();

    int jj = threadIdx.x & 15;
    for (int rr = 0; rr < 4; rr++) {
        int rl = (threadIdx.x >> 4) + rr * 16;
        int node = blockIdx.x * 64 + rl;
        float h = 0.f, di = 0.f;
        if (node < N) {
            di = dinv[node];
            h = di * (tile[rl * 16 + jj] + __bfloat162float(u[(size_t)node * H + jj])) + sb1[jj];
            h = fmaxf(h, 0.f);
        }
        float acc2 = 0.f;
#pragma unroll
        for (int kk = 0; kk < 16; kk++) {
            float hk = __shfl(h, kk, 16);
            acc2 += hk * sW2[kk * 16 + jj];
        }
        if (node < N) u2[(size_t)node * H + jj] = __float2bfloat16(di * acc2);
    }
}

// ---- layer-2 gather + finalize: log_softmax -> out (f32) ----
__global__ void gatherfin2_kernel(const unsigned* __restrict__ sorted, const int* __restrict__ rowptr,
                                  const bf16* __restrict__ u2, const float* __restrict__ dinv,
                                  const float* __restrict__ b2, float* __restrict__ out, int N) {
    __shared__ float tile[64 * 16];
    __shared__ float sb2[16];
    if (threadIdx.x < 16) sb2[threadIdx.x] = b2[threadIdx.x];

    const unsigned* uv = (const unsigned*)u2;
    int lane = threadIdx.x & 63;
    int wave = threadIdx.x >> 6;
    int j2 = lane & 7, g = lane >> 3;
    int nodeBase = blockIdx.x * 64 + wave * 16;

    for (int t = 0; t < 16; t++) {
        int node = nodeBase + t;
        float ax = 0.f, ay = 0.f;
        if (node < N) {
            int r0 = rowptr[node], r1 = rowptr[node + 1];
            int k = r0 + g;
            for (; k + 8 < r1; k += 16) {
                unsigned pa = sorted[k], pb = sorted[k + 8];
                unsigned va = uv[(size_t)(pa & 0x1FFFF) * 8 + j2];
                unsigned vb = uv[(size_t)(pb & 0x1FFFF) * 8 + j2];
                ax += bflo(va) + bflo(vb);
                ay += bfhi(va) + bfhi(vb);
            }
            if (k < r1) {
                unsigned va = uv[(size_t)(sorted[k] & 0x1FFFF) * 8 + j2];
                ax += bflo(va);
                ay += bfhi(va);
            }
        }
        ax += __shfl_xor(ax, 8);  ay += __shfl_xor(ay, 8);
        ax += __shfl_xor(ax, 16); ay += __shfl_xor(ay, 16);
        ax += __shfl_xor(ax, 32); ay += __shfl_xor(ay, 32);
        if (g == 0) {
            tile[(wave * 16 + t) * 16 + 2 * j2] = ax;
            tile[(wave * 16 + t) * 16 + 2 * j2 + 1] = ay;
        }
    }
    __syncthreads();

    int jj = threadIdx.x & 15;
    for (int rr = 0; rr < 4; rr++) {
        int rl = (threadIdx.x >> 4) + rr * 16;
        int node = blockIdx.x * 64 + rl;
        if (node >= N) continue;
        float di = dinv[node];
        float v = di * (tile[rl * 16 + jj] + __bfloat162float(u2[(size_t)node * H + jj])) + sb2[jj];

        float m = v;
#pragma unroll
        for (int off = 8; off >= 1; off >>= 1) m = fmaxf(m, __shfl_xor(m, off, 16));
        float ex = __expf(v - m);
        float s = ex;
#pragma unroll
        for (int off = 8; off >= 1; off >>= 1) s += __shfl_xor(s, off, 16);

        out[(size_t)node * H + jj] = v - m - __logf(s);
    }
}

extern "C" void kernel_launch(void* const* d_in, const int* in_sizes, int n_in,
                              void* d_out, int out_size, void* d_ws, size_t ws_size,
                              hipStream_t stream) {
    const float* x = (const float*)d_in[0];
    const int* edge_index = (const int*)d_in[1];
    const float* W1 = (const float*)d_in[2];
    const float* b1 = (const float*)d_in[3];
    const float* W2 = (const float*)d_in[4];
    const float* b2 = (const float*)d_in[5];
    float* out = (float*)d_out;

    const int N = in_sizes[0] / F_IN;        // 100000
    const int E = in_sizes[1] / 2;           // 3200000
    const int* src = edge_index;
    const int* dst = edge_index + E;
    const int NB = (N + NPB - 1) / NPB;      // 782

    // ws (4B units): dinv[N] | u[8N] | u2[8N] | packed[E] | sorted[E] |
    //                hist_t[MAX_NB*NBLK] | rowptr[N+1] | btot[NB] | base[NB+1]
    float* dinv = (float*)d_ws;
    bf16* u = (bf16*)(dinv + N);
    bf16* u2 = (bf16*)((unsigned*)u + (size_t)N * H / 2);
    unsigned* packed = (unsigned*)((unsigned*)u2 + (size_t)N * H / 2);
    unsigned* sorted = packed + E;
    int* hist_t = (int*)(sorted + E);
    int* rowptr = hist_t + (size_t)MAX_NB * NBLK;
    int* btot = rowptr + N + 1;
    int* base = btot + NB;

    histA_kernel<<<NBLK, BINT, 0, stream>>>(dst, hist_t, E, NB);
    colscan_kernel<<<NB, NBLK, 0, stream>>>(hist_t, btot);
    bucketscan_kernel<<<1, 1024, 0, stream>>>(btot, base, NB);
    binC_kernel<<<NBLK, BINT, 0, stream>>>(src, dst, hist_t, base, packed, E, NB);
    sortcsr_kernel<<<NB, 256, 0, stream>>>(packed, base, sorted, rowptr, dinv, N, E);

    xw1_kernel<<<(N + 15) / 16, 256, 0, stream>>>(x, W1, dinv, u, N);
    gatherfin1_kernel<<<(N + 63) / 64, 256, 0, stream>>>(sorted, rowptr, u, dinv, b1, W2, u2, N);
    gatherfin2_kernel<<<(N + 63) / 64, 256, 0, stream>>>(sorted, rowptr, u2, dinv, b2, out, N);
}

// Round 9
// 251.120 us; speedup vs baseline: 3.6268x; 1.0808x over previous
//
#include <hip/hip_runtime.h>
#include <hip/hip_bf16.h>
#include <math.h>

// N = 100000, E = 3.2M, F_in = 128, H = C = 16. int inputs arrive as int32.
//
// out[d] = dinv[d]*(sum_{s->d} u[s] + u[d]) + b,  u = dinv .* (h @ W).
// R3: global f32 atomics ~19.5G txn/s. R5: LDS f32 atomics ~3cy/lane.
// R6: sort->CSR->register gather. R7: bf16 messages. R8: 2-pass radix bin = 271us.
// R9: XCD-swizzled binning blocks (run boundaries stay intra-XCD), 512-thread
//     sortcsr (24 waves/CU), 4x-unrolled gather chains.

#define F_IN 128
#define H 16
#define NPB 128            // nodes per bucket
#define MAX_NB 800         // max buckets (N <= 102400)
#define NBLK 256           // binning blocks (must match hist partition)
#define BINT 1024          // binning threads per block
#define SMAX 4864          // max edges per bucket (mean 4096, +12 sigma)

typedef __hip_bfloat16 bf16;

__device__ __forceinline__ float bflo(unsigned v) { return __uint_as_float(v << 16); }
__device__ __forceinline__ float bfhi(unsigned v) { return __uint_as_float(v & 0xffff0000u); }

// physical block -> logical block so logically-adjacent blocks (adjacent output
// runs in packed[]) land on the same XCD (XCD = physical % 8 round-robin).
__device__ __forceinline__ int swz(int p) { return (p & 7) * 32 + (p >> 3); }

// ---- pass A: per-block bucket histogram -> hist_t[bucket*NBLK + block] ----
__global__ void histA_kernel(const int* __restrict__ dst, int* __restrict__ hist_t,
                             int E, int NB) {
    __shared__ int h[MAX_NB];
    int b = swz(blockIdx.x);
    long long e0 = (long long)E * b / NBLK;
    long long e1 = (long long)E * (b + 1) / NBLK;
    for (int i = threadIdx.x; i < NB; i += BINT) h[i] = 0;
    __syncthreads();
    for (long long e = e0 + threadIdx.x; e < e1; e += BINT)
        atomicAdd(&h[dst[e] >> 7], 1);
    __syncthreads();
    for (int i = threadIdx.x; i < NB; i += BINT) hist_t[i * NBLK + b] = h[i];
}

// ---- pass B1: per-bucket exclusive scan over blocks + bucket totals ----
__global__ void colscan_kernel(int* __restrict__ hist_t, int* __restrict__ btot) {
    __shared__ int s[NBLK];
    int j = blockIdx.x;
    int t = threadIdx.x;
    int v = hist_t[j * NBLK + t];
    s[t] = v;
    __syncthreads();
    for (int off = 1; off < NBLK; off <<= 1) {
        int w = (t >= off) ? s[t - off] : 0;
        __syncthreads();
        s[t] += w;
        __syncthreads();
    }
    hist_t[j * NBLK + t] = s[t] - v;
    if (t == NBLK - 1) btot[j] = s[t];
}

// ---- pass B2: exclusive scan over bucket totals -> base[] ----
__global__ void bucketscan_kernel(const int* __restrict__ btot, int* __restrict__ base, int NB) {
    __shared__ int s[1024];
    int t = threadIdx.x;
    s[t] = (t < NB) ? btot[t] : 0;
    __syncthreads();
    for (int off = 1; off < 1024; off <<= 1) {
        int v = (t >= off) ? s[t - off] : 0;
        __syncthreads();
        s[t] += v;
        __syncthreads();
    }
    if (t < NB) base[t] = s[t] - btot[t];
    if (t == NB - 1) base[NB] = s[t];
}

// ---- pass C: place edges; packed = (dst&127)<<17 | src; LDS cursors only ----
__global__ void binC_kernel(const int* __restrict__ src, const int* __restrict__ dst,
                            const int* __restrict__ hist_t, const int* __restrict__ base,
                            unsigned* __restrict__ packed, int E, int NB) {
    __shared__ int pos[MAX_NB];
    int b = swz(blockIdx.x);
    long long e0 = (long long)E * b / NBLK;
    long long e1 = (long long)E * (b + 1) / NBLK;
    for (int i = threadIdx.x; i < NB; i += BINT)
        pos[i] = base[i] + hist_t[i * NBLK + b];
    __syncthreads();
    for (long long e = e0 + threadIdx.x; e < e1; e += BINT) {
        int d = dst[e];
        int bk = d >> 7;
        int p = atomicAdd(&pos[bk], 1);
        packed[p] = (unsigned)src[e] | ((unsigned)(d & 127) << 17);
    }
}

// ---- pass D: per-bucket LDS counting sort -> sorted[], rowptr[], dinv[] ----
__global__ void sortcsr_kernel(const unsigned* __restrict__ packed, const int* __restrict__ base,
                               unsigned* __restrict__ sorted, int* __restrict__ rowptr,
                               float* __restrict__ dinv, int N, int E) {
    __shared__ unsigned ssort[SMAX];
    __shared__ int cnt[NPB], offs[NPB], cur[NPB];
    int b = blockIdx.x;
    int e0 = base[b];
    int len = base[b + 1] - e0;
    if (len > SMAX) len = SMAX;
    int T = blockDim.x;

    for (int i = threadIdx.x; i < NPB; i += T) cnt[i] = 0;
    __syncthreads();
    for (int i = threadIdx.x; i < len; i += T)
        atomicAdd(&cnt[packed[e0 + i] >> 17], 1);
    __syncthreads();
    if (threadIdx.x < NPB) offs[threadIdx.x] = cnt[threadIdx.x];
    __syncthreads();
    for (int off = 1; off < NPB; off <<= 1) {
        int v = 0;
        if (threadIdx.x < NPB && threadIdx.x >= off) v = offs[threadIdx.x - off];
        __syncthreads();
        if (threadIdx.x < NPB) offs[threadIdx.x] += v;
        __syncthreads();
    }
    if (threadIdx.x < NPB) {
        int ex = offs[threadIdx.x] - cnt[threadIdx.x];
        cur[threadIdx.x] = ex;
        int node = b * NPB + threadIdx.x;
        if (node < N) {
            rowptr[node] = e0 + ex;
            dinv[node] = rsqrtf(1.0f + (float)cnt[threadIdx.x]);
        }
    }
    __syncthreads();
    for (int i = threadIdx.x; i < len; i += T) {
        unsigned p = packed[e0 + i];
        int pos = atomicAdd(&cur[p >> 17], 1);
        ssort[pos] = p;
    }
    __syncthreads();
    for (int i = threadIdx.x; i < len; i += T) sorted[e0 + i] = ssort[i];
    if (b == 0 && threadIdx.x == 0) rowptr[N] = E;
}

// ---- u[i][j] = dinv[i] * sum_k x[i][k]*W1[k][j]  (bf16 out) ----
#define XPAD 132
__global__ void xw1_kernel(const float* __restrict__ x, const float* __restrict__ W1,
                           const float* __restrict__ dinv, bf16* __restrict__ u, int n) {
    __shared__ float sW1[F_IN * H];
    __shared__ float sx[16 * XPAD];
    for (int t = threadIdx.x; t < F_IN * H; t += blockDim.x) sW1[t] = W1[t];

    int basei = blockIdx.x * 16;
    for (int idx = threadIdx.x; idx < 512; idx += 256) {
        int r = idx >> 5;
        int kk = (idx & 31) << 2;
        int row = basei + r;
        float4 v = make_float4(0.f, 0.f, 0.f, 0.f);
        if (row < n) v = *(const float4*)(x + (size_t)row * F_IN + kk);
        *(float4*)(sx + r * XPAD + kk) = v;
    }
    __syncthreads();

    int r = threadIdx.x >> 4;
    int j = threadIdx.x & 15;
    int row = basei + r;
    if (row >= n) return;

    const float* xr = sx + r * XPAD;
    float acc = 0.0f;
#pragma unroll 16
    for (int k = 0; k < F_IN; k++) acc += xr[k] * sW1[k * H + j];
    u[(size_t)row * H + j] = __float2bfloat16(dinv[row] * acc);
}

// ---- layer-1 gather + finalize: lane = (ch-pair 0..7) x (slot 0..7),
//      4x unrolled -> up to 8 independent loads in flight per lane ----
__global__ void gatherfin1_kernel(const unsigned* __restrict__ sorted, const int* __restrict__ rowptr,
                                  const bf16* __restrict__ u, const float* __restrict__ dinv,
                                  const float* __restrict__ b1, const float* __restrict__ W2,
                                  bf16* __restrict__ u2, int N) {
    __shared__ float tile[64 * 16];
    __shared__ float sW2[256];
    __shared__ float sb1[16];
    sW2[threadIdx.x] = W2[threadIdx.x];
    if (threadIdx.x < 16) sb1[threadIdx.x] = b1[threadIdx.x];

    const unsigned* uv = (const unsigned*)u;   // [node*8 + j2] channel pairs
    int lane = threadIdx.x & 63;
    int wave = threadIdx.x >> 6;
    int j2 = lane & 7, g = lane >> 3;
    int nodeBase = blockIdx.x * 64 + wave * 16;

    for (int t = 0; t < 16; t++) {
        int node = nodeBase + t;
        float ax = 0.f, ay = 0.f;
        if (node < N) {
            int r0 = rowptr[node], r1 = rowptr[node + 1];
            int k = r0 + g;
            for (; k + 24 < r1; k += 32) {
                unsigned p0 = sorted[k], p1 = sorted[k + 8];
                unsigned p2 = sorted[k + 16], p3 = sorted[k + 24];
                unsigned v0 = uv[(size_t)(p0 & 0x1FFFF) * 8 + j2];
                unsigned v1 = uv[(size_t)(p1 & 0x1FFFF) * 8 + j2];
                unsigned v2 = uv[(size_t)(p2 & 0x1FFFF) * 8 + j2];
                unsigned v3 = uv[(size_t)(p3 & 0x1FFFF) * 8 + j2];
                ax += bflo(v0) + bflo(v1) + bflo(v2) + bflo(v3);
                ay += bfhi(v0) + bfhi(v1) + bfhi(v2) + bfhi(v3);
            }
            for (; k < r1; k += 8) {
                unsigned va = uv[(size_t)(sorted[k] & 0x1FFFF) * 8 + j2];
                ax += bflo(va);
                ay += bfhi(va);
            }
        }
        ax += __shfl_xor(ax, 8);  ay += __shfl_xor(ay, 8);
        ax += __shfl_xor(ax, 16); ay += __shfl_xor(ay, 16);
        ax += __shfl_xor(ax, 32); ay += __shfl_xor(ay, 32);
        if (g == 0) {
            tile[(wave * 16 + t) * 16 + 2 * j2] = ax;
            tile[(wave * 16 + t) * 16 + 2 * j2 + 1] = ay;
        }
    }
    __syncthreads();

    int jj = threadIdx.x & 15;
    for (int rr = 0; rr < 4; rr++) {
        int rl = (threadIdx.x >> 4) + rr * 16;
        int node = blockIdx.x * 64 + rl;
        float h = 0.f, di = 0.f;
        if (node < N) {
            di = dinv[node];
            h = di * (tile[rl * 16 + jj] + __bfloat162float(u[(size_t)node * H + jj])) + sb1[jj];
            h = fmaxf(h, 0.f);
        }
        float acc2 = 0.f;
#pragma unroll
        for (int kk = 0; kk < 16; kk++) {
            float hk = __shfl(h, kk, 16);
            acc2 += hk * sW2[kk * 16 + jj];
        }
        if (node < N) u2[(size_t)node * H + jj] = __float2bfloat16(di * acc2);
    }
}

// ---- layer-2 gather + finalize: log_softmax -> out (f32) ----
__global__ void gatherfin2_kernel(const unsigned* __restrict__ sorted, const int* __restrict__ rowptr,
                                  const bf16* __restrict__ u2, const float* __restrict__ dinv,
                                  const float* __restrict__ b2, float* __restrict__ out, int N) {
    __shared__ float tile[64 * 16];
    __shared__ float sb2[16];
    if (threadIdx.x < 16) sb2[threadIdx.x] = b2[threadIdx.x];

    const unsigned* uv = (const unsigned*)u2;
    int lane = threadIdx.x & 63;
    int wave = threadIdx.x >> 6;
    int j2 = lane & 7, g = lane >> 3;
    int nodeBase = blockIdx.x * 64 + wave * 16;

    for (int t = 0; t < 16; t++) {
        int node = nodeBase + t;
        float ax = 0.f, ay = 0.f;
        if (node < N) {
            int r0 = rowptr[node], r1 = rowptr[node + 1];
            int k = r0 + g;
            for (; k + 24 < r1; k += 32) {
                unsigned p0 = sorted[k], p1 = sorted[k + 8];
                unsigned p2 = sorted[k + 16], p3 = sorted[k + 24];
                unsigned v0 = uv[(size_t)(p0 & 0x1FFFF) * 8 + j2];
                unsigned v1 = uv[(size_t)(p1 & 0x1FFFF) * 8 + j2];
                unsigned v2 = uv[(size_t)(p2 & 0x1FFFF) * 8 + j2];
                unsigned v3 = uv[(size_t)(p3 & 0x1FFFF) * 8 + j2];
                ax += bflo(v0) + bflo(v1) + bflo(v2) + bflo(v3);
                ay += bfhi(v0) + bfhi(v1) + bfhi(v2) + bfhi(v3);
            }
            for (; k < r1; k += 8) {
                unsigned va = uv[(size_t)(sorted[k] & 0x1FFFF) * 8 + j2];
                ax += bflo(va);
                ay += bfhi(va);
            }
        }
        ax += __shfl_xor(ax, 8);  ay += __shfl_xor(ay, 8);
        ax += __shfl_xor(ax, 16); ay += __shfl_xor(ay, 16);
        ax += __shfl_xor(ax, 32); ay += __shfl_xor(ay, 32);
        if (g == 0) {
            tile[(wave * 16 + t) * 16 + 2 * j2] = ax;
            tile[(wave * 16 + t) * 16 + 2 * j2 + 1] = ay;
        }
    }
    __syncthreads();

    int jj = threadIdx.x & 15;
    for (int rr = 0; rr < 4; rr++) {
        int rl = (threadIdx.x >> 4) + rr * 16;
        int node = blockIdx.x * 64 + rl;
        if (node >= N) continue;
        float di = dinv[node];
        float v = di * (tile[rl * 16 + jj] + __bfloat162float(u2[(size_t)node * H + jj])) + sb2[jj];

        float m = v;
#pragma unroll
        for (int off = 8; off >= 1; off >>= 1) m = fmaxf(m, __shfl_xor(m, off, 16));
        float ex = __expf(v - m);
        float s = ex;
#pragma unroll
        for (int off = 8; off >= 1; off >>= 1) s += __shfl_xor(s, off, 16);

        out[(size_t)node * H + jj] = v - m - __logf(s);
    }
}

extern "C" void kernel_launch(void* const* d_in, const int* in_sizes, int n_in,
                              void* d_out, int out_size, void* d_ws, size_t ws_size,
                              hipStream_t stream) {
    const float* x = (const float*)d_in[0];
    const int* edge_index = (const int*)d_in[1];
    const float* W1 = (const float*)d_in[2];
    const float* b1 = (const float*)d_in[3];
    const float* W2 = (const float*)d_in[4];
    const float* b2 = (const float*)d_in[5];
    float* out = (float*)d_out;

    const int N = in_sizes[0] / F_IN;        // 100000
    const int E = in_sizes[1] / 2;           // 3200000
    const int* src = edge_index;
    const int* dst = edge_index + E;
    const int NB = (N + NPB - 1) / NPB;      // 782

    // ws (4B units): dinv[N] | u[8N] | u2[8N] | packed[E] | sorted[E] |
    //                hist_t[MAX_NB*NBLK] | rowptr[N+1] | btot[NB] | base[NB+1]
    float* dinv = (float*)d_ws;
    bf16* u = (bf16*)(dinv + N);
    bf16* u2 = (bf16*)((unsigned*)u + (size_t)N * H / 2);
    unsigned* packed = (unsigned*)((unsigned*)u2 + (size_t)N * H / 2);
    unsigned* sorted = packed + E;
    int* hist_t = (int*)(sorted + E);
    int* rowptr = hist_t + (size_t)MAX_NB * NBLK;
    int* btot = rowptr + N + 1;
    int* base = btot + NB;

    histA_kernel<<<NBLK, BINT, 0, stream>>>(dst, hist_t, E, NB);
    colscan_kernel<<<NB, NBLK, 0, stream>>>(hist_t, btot);
    bucketscan_kernel<<<1, 1024, 0, stream>>>(btot, base, NB);
    binC_kernel<<<NBLK, BINT, 0, stream>>>(src, dst, hist_t, base, packed, E, NB);
    sortcsr_kernel<<<NB, 512, 0, stream>>>(packed, base, sorted, rowptr, dinv, N, E);

    xw1_kernel<<<(N + 15) / 16, 256, 0, stream>>>(x, W1, dinv, u, N);
    gatherfin1_kernel<<<(N + 63) / 64, 256, 0, stream>>>(sorted, rowptr, u, dinv, b1, W2, u2, N);
    gatherfin2_kernel<<<(N + 63) / 64, 256, 0, stream>>>(sorted, rowptr, u2, dinv, b2, out, N);
}

// Round 10
// 241.872 us; speedup vs baseline: 3.7655x; 1.0382x over previous
//
#include <hip/hip_runtime.h>
#include <hip/hip_bf16.h>
#include <math.h>

// N = 100000, E = 3.2M, F_in = 128, H = C = 16. int inputs arrive as int32.
//
// out[d] = dinv[d]*(sum_{s->d} u[s] + u[d]) + b,  u = dinv .* (h @ W).
// R3: global f32 atomics ~19.5G txn/s. R5: LDS f32 atomics ~3cy/lane.
// R6: sort->CSR->register gather. R7: bf16 messages. R8: 2-pass radix bin.
// R9: XCD-swizzled bins = 251us; gather unroll was a wash (latency still
//     exposed: sorted->uv->reduce issued back-to-back per node).
// R10: depth-2 software pipeline across nodes in the gather kernels:
//     prefetch sorted[t+1] while consuming uv[t] (issued last iteration).

#define F_IN 128
#define H 16
#define NPB 128            // nodes per bucket
#define MAX_NB 800         // max buckets (N <= 102400)
#define NBLK 256           // binning blocks (must match hist partition)
#define BINT 1024          // binning threads per block
#define SMAX 4864          // max edges per bucket (mean 4096, +12 sigma)
#define PFD 6              // prefetch depth: 8 slots * 6 = 48 edges covered

typedef __hip_bfloat16 bf16;

__device__ __forceinline__ float bflo(unsigned v) { return __uint_as_float(v << 16); }
__device__ __forceinline__ float bfhi(unsigned v) { return __uint_as_float(v & 0xffff0000u); }

// physical block -> logical block so logically-adjacent blocks (adjacent output
// runs in packed[]) land on the same XCD (XCD = physical % 8 round-robin).
__device__ __forceinline__ int swz(int p) { return (p & 7) * 32 + (p >> 3); }

// ---- pass A: per-block bucket histogram -> hist_t[bucket*NBLK + block] ----
__global__ void histA_kernel(const int* __restrict__ dst, int* __restrict__ hist_t,
                             int E, int NB) {
    __shared__ int h[MAX_NB];
    int b = swz(blockIdx.x);
    long long e0 = (long long)E * b / NBLK;
    long long e1 = (long long)E * (b + 1) / NBLK;
    for (int i = threadIdx.x; i < NB; i += BINT) h[i] = 0;
    __syncthreads();
    for (long long e = e0 + threadIdx.x; e < e1; e += BINT)
        atomicAdd(&h[dst[e] >> 7], 1);
    __syncthreads();
    for (int i = threadIdx.x; i < NB; i += BINT) hist_t[i * NBLK + b] = h[i];
}

// ---- pass B1: per-bucket exclusive scan over blocks + bucket totals ----
__global__ void colscan_kernel(int* __restrict__ hist_t, int* __restrict__ btot) {
    __shared__ int s[NBLK];
    int j = blockIdx.x;
    int t = threadIdx.x;
    int v = hist_t[j * NBLK + t];
    s[t] = v;
    __syncthreads();
    for (int off = 1; off < NBLK; off <<= 1) {
        int w = (t >= off) ? s[t - off] : 0;
        __syncthreads();
        s[t] += w;
        __syncthreads();
    }
    hist_t[j * NBLK + t] = s[t] - v;
    if (t == NBLK - 1) btot[j] = s[t];
}

// ---- pass B2: exclusive scan over bucket totals -> base[] ----
__global__ void bucketscan_kernel(const int* __restrict__ btot, int* __restrict__ base, int NB) {
    __shared__ int s[1024];
    int t = threadIdx.x;
    s[t] = (t < NB) ? btot[t] : 0;
    __syncthreads();
    for (int off = 1; off < 1024; off <<= 1) {
        int v = (t >= off) ? s[t - off] : 0;
        __syncthreads();
        s[t] += v;
        __syncthreads();
    }
    if (t < NB) base[t] = s[t] - btot[t];
    if (t == NB - 1) base[NB] = s[t];
}

// ---- pass C: place edges; packed = (dst&127)<<17 | src; LDS cursors only ----
__global__ void binC_kernel(const int* __restrict__ src, const int* __restrict__ dst,
                            const int* __restrict__ hist_t, const int* __restrict__ base,
                            unsigned* __restrict__ packed, int E, int NB) {
    __shared__ int pos[MAX_NB];
    int b = swz(blockIdx.x);
    long long e0 = (long long)E * b / NBLK;
    long long e1 = (long long)E * (b + 1) / NBLK;
    for (int i = threadIdx.x; i < NB; i += BINT)
        pos[i] = base[i] + hist_t[i * NBLK + b];
    __syncthreads();
    for (long long e = e0 + threadIdx.x; e < e1; e += BINT) {
        int d = dst[e];
        int bk = d >> 7;
        int p = atomicAdd(&pos[bk], 1);
        packed[p] = (unsigned)src[e] | ((unsigned)(d & 127) << 17);
    }
}

// ---- pass D: per-bucket LDS counting sort -> sorted[], rowptr[], dinv[] ----
__global__ void sortcsr_kernel(const unsigned* __restrict__ packed, const int* __restrict__ base,
                               unsigned* __restrict__ sorted, int* __restrict__ rowptr,
                               float* __restrict__ dinv, int N, int E) {
    __shared__ unsigned ssort[SMAX];
    __shared__ int cnt[NPB], offs[NPB], cur[NPB];
    int b = blockIdx.x;
    int e0 = base[b];
    int len = base[b + 1] - e0;
    if (len > SMAX) len = SMAX;
    int T = blockDim.x;

    for (int i = threadIdx.x; i < NPB; i += T) cnt[i] = 0;
    __syncthreads();
    for (int i = threadIdx.x; i < len; i += T)
        atomicAdd(&cnt[packed[e0 + i] >> 17], 1);
    __syncthreads();
    if (threadIdx.x < NPB) offs[threadIdx.x] = cnt[threadIdx.x];
    __syncthreads();
    for (int off = 1; off < NPB; off <<= 1) {
        int v = 0;
        if (threadIdx.x < NPB && threadIdx.x >= off) v = offs[threadIdx.x - off];
        __syncthreads();
        if (threadIdx.x < NPB) offs[threadIdx.x] += v;
        __syncthreads();
    }
    if (threadIdx.x < NPB) {
        int ex = offs[threadIdx.x] - cnt[threadIdx.x];
        cur[threadIdx.x] = ex;
        int node = b * NPB + threadIdx.x;
        if (node < N) {
            rowptr[node] = e0 + ex;
            dinv[node] = rsqrtf(1.0f + (float)cnt[threadIdx.x]);
        }
    }
    __syncthreads();
    for (int i = threadIdx.x; i < len; i += T) {
        unsigned p = packed[e0 + i];
        int pos = atomicAdd(&cur[p >> 17], 1);
        ssort[pos] = p;
    }
    __syncthreads();
    for (int i = threadIdx.x; i < len; i += T) sorted[e0 + i] = ssort[i];
    if (b == 0 && threadIdx.x == 0) rowptr[N] = E;
}

// ---- u[i][j] = dinv[i] * sum_k x[i][k]*W1[k][j]  (bf16 out) ----
#define XPAD 132
__global__ void xw1_kernel(const float* __restrict__ x, const float* __restrict__ W1,
                           const float* __restrict__ dinv, bf16* __restrict__ u, int n) {
    __shared__ float sW1[F_IN * H];
    __shared__ float sx[16 * XPAD];
    for (int t = threadIdx.x; t < F_IN * H; t += blockDim.x) sW1[t] = W1[t];

    int basei = blockIdx.x * 16;
    for (int idx = threadIdx.x; idx < 512; idx += 256) {
        int r = idx >> 5;
        int kk = (idx & 31) << 2;
        int row = basei + r;
        float4 v = make_float4(0.f, 0.f, 0.f, 0.f);
        if (row < n) v = *(const float4*)(x + (size_t)row * F_IN + kk);
        *(float4*)(sx + r * XPAD + kk) = v;
    }
    __syncthreads();

    int r = threadIdx.x >> 4;
    int j = threadIdx.x & 15;
    int row = basei + r;
    if (row >= n) return;

    const float* xr = sx + r * XPAD;
    float acc = 0.0f;
#pragma unroll 16
    for (int k = 0; k < F_IN; k++) acc += xr[k] * sW1[k * H + j];
    u[(size_t)row * H + j] = __float2bfloat16(dinv[row] * acc);
}

// ================= pipelined gather core (shared by both layers) =============
// lane = (ch-pair j2 0..7) x (slot g 0..7). Depth-2 pipeline over the 16 nodes
// a wave owns: prefetch sorted[t+1] while consuming uv[t] issued last iter.
#define GATHER_TILE(UVPTR)                                                      \
    int lane = threadIdx.x & 63;                                                \
    int wave = threadIdx.x >> 6;                                                \
    int j2 = lane & 7, g = lane >> 3;                                           \
    int nodeBase = blockIdx.x * 64 + wave * 16;                                 \
    int r0c = 0, r1c = 0;                                                       \
    unsigned svc[PFD]; unsigned uvc[PFD];                                       \
    {   int node = nodeBase;                                                    \
        if (node < N) { r0c = rowptr[node]; r1c = rowptr[node + 1]; }           \
        _Pragma("unroll")                                                       \
        for (int m = 0; m < PFD; m++) {                                         \
            int k = r0c + g + 8 * m;                                            \
            if (k < r1c) svc[m] = sorted[k];                                    \
        }                                                                       \
        _Pragma("unroll")                                                       \
        for (int m = 0; m < PFD; m++) {                                         \
            int k = r0c + g + 8 * m;                                            \
            if (k < r1c) uvc[m] = UVPTR[(size_t)(svc[m] & 0x1FFFF) * 8 + j2];   \
        }                                                                       \
    }                                                                           \
    for (int t = 0; t < 16; t++) {                                              \
        int r0n = 0, r1n = 0;                                                   \
        unsigned svn[PFD];                                                      \
        if (t < 15) {                                                           \
            int nn = nodeBase + t + 1;                                          \
            if (nn < N) { r0n = rowptr[nn]; r1n = rowptr[nn + 1]; }             \
            _Pragma("unroll")                                                   \
            for (int m = 0; m < PFD; m++) {                                     \
                int k = r0n + g + 8 * m;                                        \
                if (k < r1n) svn[m] = sorted[k];                                \
            }                                                                   \
        }                                                                       \
        float ax = 0.f, ay = 0.f;                                               \
        _Pragma("unroll")                                                       \
        for (int m = 0; m < PFD; m++) {                                         \
            int k = r0c + g + 8 * m;                                            \
            if (k < r1c) { ax += bflo(uvc[m]); ay += bfhi(uvc[m]); }            \
        }                                                                       \
        for (int k = r0c + g + 8 * PFD; k < r1c; k += 8) {                      \
            unsigned va = UVPTR[(size_t)(sorted[k] & 0x1FFFF) * 8 + j2];        \
            ax += bflo(va); ay += bfhi(va);                                     \
        }                                                                       \
        ax += __shfl_xor(ax, 8);  ay += __shfl_xor(ay, 8);                      \
        ax += __shfl_xor(ax, 16); ay += __shfl_xor(ay, 16);                     \
        ax += __shfl_xor(ax, 32); ay += __shfl_xor(ay, 32);                     \
        if (g == 0) {                                                           \
            tile[(wave * 16 + t) * 16 + 2 * j2] = ax;                           \
            tile[(wave * 16 + t) * 16 + 2 * j2 + 1] = ay;                       \
        }                                                                       \
        if (t < 15) {                                                           \
            r0c = r0n; r1c = r1n;                                               \
            _Pragma("unroll")                                                   \
            for (int m = 0; m < PFD; m++) {                                     \
                int k = r0n + g + 8 * m;                                        \
                svc[m] = svn[m];                                                \
                if (k < r1n) uvc[m] = UVPTR[(size_t)(svn[m] & 0x1FFFF) * 8 + j2]; \
            }                                                                   \
        }                                                                       \
    }

// ---- layer-1 gather + finalize ----
__global__ void gatherfin1_kernel(const unsigned* __restrict__ sorted, const int* __restrict__ rowptr,
                                  const bf16* __restrict__ u, const float* __restrict__ dinv,
                                  const float* __restrict__ b1, const float* __restrict__ W2,
                                  bf16* __restrict__ u2, int N) {
    __shared__ float tile[64 * 16];
    __shared__ float sW2[256];
    __shared__ float sb1[16];
    sW2[threadIdx.x] = W2[threadIdx.x];
    if (threadIdx.x < 16) sb1[threadIdx.x] = b1[threadIdx.x];

    const unsigned* uvp = (const unsigned*)u;   // [node*8 + j2] channel pairs
    GATHER_TILE(uvp)
    __syncthreads();

    int jj = threadIdx.x & 15;
    for (int rr = 0; rr < 4; rr++) {
        int rl = (threadIdx.x >> 4) + rr * 16;
        int node = blockIdx.x * 64 + rl;
        float h = 0.f, di = 0.f;
        if (node < N) {
            di = dinv[node];
            h = di * (tile[rl * 16 + jj] + __bfloat162float(u[(size_t)node * H + jj])) + sb1[jj];
            h = fmaxf(h, 0.f);
        }
        float acc2 = 0.f;
#pragma unroll
        for (int kk = 0; kk < 16; kk++) {
            float hk = __shfl(h, kk, 16);
            acc2 += hk * sW2[kk * 16 + jj];
        }
        if (node < N) u2[(size_t)node * H + jj] = __float2bfloat16(di * acc2);
    }
}

// ---- layer-2 gather + finalize: log_softmax -> out (f32) ----
__global__ void gatherfin2_kernel(const unsigned* __restrict__ sorted, const int* __restrict__ rowptr,
                                  const bf16* __restrict__ u2, const float* __restrict__ dinv,
                                  const float* __restrict__ b2, float* __restrict__ out, int N) {
    __shared__ float tile[64 * 16];
    __shared__ float sb2[16];
    if (threadIdx.x < 16) sb2[threadIdx.x] = b2[threadIdx.x];

    const unsigned* uvp = (const unsigned*)u2;
    GATHER_TILE(uvp)
    __syncthreads();

    int jj = threadIdx.x & 15;
    for (int rr = 0; rr < 4; rr++) {
        int rl = (threadIdx.x >> 4) + rr * 16;
        int node = blockIdx.x * 64 + rl;
        if (node >= N) continue;
        float di = dinv[node];
        float v = di * (tile[rl * 16 + jj] + __bfloat162float(u2[(size_t)node * H + jj])) + sb2[jj];

        float m = v;
#pragma unroll
        for (int off = 8; off >= 1; off >>= 1) m = fmaxf(m, __shfl_xor(m, off, 16));
        float ex = __expf(v - m);
        float s = ex;
#pragma unroll
        for (int off = 8; off >= 1; off >>= 1) s += __shfl_xor(s, off, 16);

        out[(size_t)node * H + jj] = v - m - __logf(s);
    }
}

extern "C" void kernel_launch(void* const* d_in, const int* in_sizes, int n_in,
                              void* d_out, int out_size, void* d_ws, size_t ws_size,
                              hipStream_t stream) {
    const float* x = (const float*)d_in[0];
    const int* edge_index = (const int*)d_in[1];
    const float* W1 = (const float*)d_in[2];
    const float* b1 = (const float*)d_in[3];
    const float* W2 = (const float*)d_in[4];
    const float* b2 = (const float*)d_in[5];
    float* out = (float*)d_out;

    const int N = in_sizes[0] / F_IN;        // 100000
    const int E = in_sizes[1] / 2;           // 3200000
    const int* src = edge_index;
    const int* dst = edge_index + E;
    const int NB = (N + NPB - 1) / NPB;      // 782

    // ws (4B units): dinv[N] | u[8N] | u2[8N] | packed[E] | sorted[E] |
    //                hist_t[MAX_NB*NBLK] | rowptr[N+1] | btot[NB] | base[NB+1]
    float* dinv = (float*)d_ws;
    bf16* u = (bf16*)(dinv + N);
    bf16* u2 = (bf16*)((unsigned*)u + (size_t)N * H / 2);
    unsigned* packed = (unsigned*)((unsigned*)u2 + (size_t)N * H / 2);
    unsigned* sorted = packed + E;
    int* hist_t = (int*)(sorted + E);
    int* rowptr = hist_t + (size_t)MAX_NB * NBLK;
    int* btot = rowptr + N + 1;
    int* base = btot + NB;

    histA_kernel<<<NBLK, BINT, 0, stream>>>(dst, hist_t, E, NB);
    colscan_kernel<<<NB, NBLK, 0, stream>>>(hist_t, btot);
    bucketscan_kernel<<<1, 1024, 0, stream>>>(btot, base, NB);
    binC_kernel<<<NBLK, BINT, 0, stream>>>(src, dst, hist_t, base, packed, E, NB);
    sortcsr_kernel<<<NB, 512, 0, stream>>>(packed, base, sorted, rowptr, dinv, N, E);

    xw1_kernel<<<(N + 15) / 16, 256, 0, stream>>>(x, W1, dinv, u, N);
    gatherfin1_kernel<<<(N + 63) / 64, 256, 0, stream>>>(sorted, rowptr, u, dinv, b1, W2, u2, N);
    gatherfin2_kernel<<<(N + 63) / 64, 256, 0, stream>>>(sorted, rowptr, u2, dinv, b2, out, N);
}